// Round 2
// baseline (5518.600 us; speedup 1.0000x reference)
//
#include <hip/hip_runtime.h>
#include <cstdint>
#include <cstddef>

#define DD 256   // feature dim

// ---------- helpers --------------------------------------------------------
__device__ __forceinline__ float4 ldrow(const float* __restrict__ base, int row, int lane) {
    return ((const float4*)(base + (size_t)row * DD))[lane];
}
__device__ __forceinline__ float4 mul4(float4 a, float4 b) {
    return make_float4(a.x * b.x, a.y * b.y, a.z * b.z, a.w * b.w);
}
__device__ __forceinline__ float4 add4(float4 a, float4 b) {
    return make_float4(a.x + b.x, a.y + b.y, a.z + b.z, a.w + b.w);
}
__device__ __forceinline__ void atomic_add4(float* p, float4 v) {
    unsafeAtomicAdd(p + 0, v.x);
    unsafeAtomicAdd(p + 1, v.y);
    unsafeAtomicAdd(p + 2, v.z);
    unsafeAtomicAdd(p + 3, v.w);
}

// ---------- h2 materialization: h2[q] = feat[c2a[q]] * feat[c2b[q]] --------
__global__ void k_h2(const float* __restrict__ feat, const int* __restrict__ c2a,
                     const int* __restrict__ c2b, float* __restrict__ h2, int n2) {
    int q = blockIdx.x * 4 + (threadIdx.x >> 6);
    int lane = threadIdx.x & 63;
    if (q >= n2) return;
    float4 v = mul4(ldrow(feat, c2a[q], lane), ldrow(feat, c2b[q], lane));
    ((float4*)(h2 + (size_t)q * DD))[lane] = v;
}

// ---------- up4+down4 (h2-backed): acc3[c4a[p]] += v; acc3[c4b[p]] += v ----
// v = h3[c4a[p]] * h3[c4b[p]], h3[j] = h2[c3a[j]] * h2[c3b[j]]
__global__ void k_up4_h2(const float* __restrict__ h2,
                         const int* __restrict__ c3a, const int* __restrict__ c3b,
                         const int* __restrict__ c4a, const int* __restrict__ c4b,
                         float* __restrict__ acc3, int n4) {
    int p = blockIdx.x * 4 + (threadIdx.x >> 6);
    int lane = threadIdx.x & 63;
    if (p >= n4) return;
    int j1 = c4a[p], j2 = c4b[p];
    int q11 = c3a[j1], q12 = c3b[j1], q21 = c3a[j2], q22 = c3b[j2];
    float4 v = mul4(mul4(ldrow(h2, q11, lane), ldrow(h2, q12, lane)),
                    mul4(ldrow(h2, q21, lane), ldrow(h2, q22, lane)));
    atomic_add4(acc3 + (size_t)j1 * DD + lane * 4, v);
    atomic_add4(acc3 + (size_t)j2 * DD + lane * 4, v);
}

// ---------- up4+down4 (feat-recompute, dest-range-chunked) -----------------
__global__ void k_up4_feat(const float* __restrict__ feat,
                           const int* __restrict__ c2a, const int* __restrict__ c2b,
                           const int* __restrict__ c3a, const int* __restrict__ c3b,
                           const int* __restrict__ c4a, const int* __restrict__ c4b,
                           float* __restrict__ acc3, int n4, int lo, int hi) {
    int p = blockIdx.x * 4 + (threadIdx.x >> 6);
    int lane = threadIdx.x & 63;
    if (p >= n4) return;
    int j1 = c4a[p], j2 = c4b[p];
    bool in1 = (j1 >= lo && j1 < hi), in2 = (j2 >= lo && j2 < hi);
    if (!in1 && !in2) return;  // wave-uniform exit
    int q11 = c3a[j1], q12 = c3b[j1], q21 = c3a[j2], q22 = c3b[j2];
    float4 h2a = mul4(ldrow(feat, c2a[q11], lane), ldrow(feat, c2b[q11], lane));
    float4 h2b = mul4(ldrow(feat, c2a[q12], lane), ldrow(feat, c2b[q12], lane));
    float4 h2c = mul4(ldrow(feat, c2a[q21], lane), ldrow(feat, c2b[q21], lane));
    float4 h2d = mul4(ldrow(feat, c2a[q22], lane), ldrow(feat, c2b[q22], lane));
    float4 v = mul4(mul4(h2a, h2b), mul4(h2c, h2d));
    if (in1) atomic_add4(acc3 + (size_t)(j1 - lo) * DD + lane * 4, v);
    if (in2) atomic_add4(acc3 + (size_t)(j2 - lo) * DD + lane * 4, v);
}

// ---------- down3 direct to out (h2-backed) --------------------------------
// v = h3[j] + acc3[j]; out[c2a[q1]] += v; out[c2b[q1]] += v; likewise q2
__global__ void k_down3_h2(const float* __restrict__ h2,
                           const float* __restrict__ acc3,
                           const int* __restrict__ c2a, const int* __restrict__ c2b,
                           const int* __restrict__ c3a, const int* __restrict__ c3b,
                           float* __restrict__ out, int n3) {
    int j = blockIdx.x * 4 + (threadIdx.x >> 6);
    int lane = threadIdx.x & 63;
    if (j >= n3) return;
    int q1 = c3a[j], q2 = c3b[j];
    float4 v = add4(mul4(ldrow(h2, q1, lane), ldrow(h2, q2, lane)),
                    ldrow(acc3, j, lane));
    int d0 = c2a[q1], d1 = c2b[q1], d2 = c2a[q2], d3 = c2b[q2];
    atomic_add4(out + (size_t)d0 * DD + lane * 4, v);
    atomic_add4(out + (size_t)d1 * DD + lane * 4, v);
    atomic_add4(out + (size_t)d2 * DD + lane * 4, v);
    atomic_add4(out + (size_t)d3 * DD + lane * 4, v);
}

// ---------- down3 direct to out (feat-recompute, range) --------------------
__global__ void k_down3_feat(const float* __restrict__ feat,
                             const float* __restrict__ acc3,
                             const int* __restrict__ c2a, const int* __restrict__ c2b,
                             const int* __restrict__ c3a, const int* __restrict__ c3b,
                             float* __restrict__ out, int lo, int hi) {
    int j = lo + blockIdx.x * 4 + (threadIdx.x >> 6);
    int lane = threadIdx.x & 63;
    if (j >= hi) return;
    int q1 = c3a[j], q2 = c3b[j];
    float4 h2a = mul4(ldrow(feat, c2a[q1], lane), ldrow(feat, c2b[q1], lane));
    float4 h2b = mul4(ldrow(feat, c2a[q2], lane), ldrow(feat, c2b[q2], lane));
    float4 v = add4(mul4(h2a, h2b), ldrow(acc3, j - lo, lane));
    int d0 = c2a[q1], d1 = c2b[q1], d2 = c2a[q2], d3 = c2b[q2];
    atomic_add4(out + (size_t)d0 * DD + lane * 4, v);
    atomic_add4(out + (size_t)d1 * DD + lane * 4, v);
    atomic_add4(out + (size_t)d2 * DD + lane * 4, v);
    atomic_add4(out + (size_t)d3 * DD + lane * 4, v);
}

// ---------- down2 direct to out --------------------------------------------
__global__ void k_down2_h2(const float* __restrict__ h2,
                           const int* __restrict__ c2a, const int* __restrict__ c2b,
                           float* __restrict__ out, int n2) {
    int q = blockIdx.x * 4 + (threadIdx.x >> 6);
    int lane = threadIdx.x & 63;
    if (q >= n2) return;
    float4 v = ldrow(h2, q, lane);
    atomic_add4(out + (size_t)c2a[q] * DD + lane * 4, v);
    atomic_add4(out + (size_t)c2b[q] * DD + lane * 4, v);
}

__global__ void k_down2_feat(const float* __restrict__ feat,
                             const int* __restrict__ c2a, const int* __restrict__ c2b,
                             float* __restrict__ out, int n2) {
    int q = blockIdx.x * 4 + (threadIdx.x >> 6);
    int lane = threadIdx.x & 63;
    if (q >= n2) return;
    int ra = c2a[q], rb = c2b[q];
    float4 v = mul4(ldrow(feat, ra, lane), ldrow(feat, rb, lane));
    atomic_add4(out + (size_t)ra * DD + lane * 4, v);
    atomic_add4(out + (size_t)rb * DD + lane * 4, v);
}

// ---------- GEMM + bias + SiLU, in-place on h [n1][256] --------------------
__device__ __forceinline__ float silu_f(float x) { return x / (1.0f + expf(-x)); }

__global__ __launch_bounds__(256) void k_gemm_silu(float* __restrict__ h,
                                                   const float* __restrict__ W,
                                                   const float* __restrict__ bias,
                                                   int n1) {
    __shared__ float As[32 * DD];  // 32 KB
    const int t = threadIdx.x;
    const int row0 = blockIdx.x * 32;

    const float4* hv = (const float4*)h;
    float4* As4 = (float4*)As;
#pragma unroll
    for (int i = 0; i < 8; ++i) {
        int idx = t + i * 256;
        int r = idx >> 6, c = idx & 63;
        int gr = row0 + r;
        float4 v = make_float4(0.f, 0.f, 0.f, 0.f);
        if (gr < n1) v = hv[(size_t)gr * 64 + c];
        As4[idx] = v;
    }
    __syncthreads();

    const int rg = t >> 6;
    const int cg = t & 63;
    const float4* Wv = (const float4*)W;

    float4 acc[8];
#pragma unroll
    for (int r = 0; r < 8; ++r) acc[r] = make_float4(0.f, 0.f, 0.f, 0.f);

    for (int k = 0; k < DD; k += 4) {
        float4 a[8];
#pragma unroll
        for (int r = 0; r < 8; ++r)
            a[r] = *(const float4*)&As[(rg * 8 + r) * DD + k];
#pragma unroll
        for (int kk = 0; kk < 4; ++kk) {
            float4 w = Wv[(size_t)(k + kk) * 64 + cg];
#pragma unroll
            for (int r = 0; r < 8; ++r) {
                float av = (kk == 0) ? a[r].x : (kk == 1) ? a[r].y
                         : (kk == 2) ? a[r].z : a[r].w;
                acc[r].x += av * w.x;
                acc[r].y += av * w.y;
                acc[r].z += av * w.z;
                acc[r].w += av * w.w;
            }
        }
    }

    float4 bb = ((const float4*)bias)[cg];
    float4* ho = (float4*)h;
#pragma unroll
    for (int r = 0; r < 8; ++r) {
        int gr = row0 + rg * 8 + r;
        if (gr >= n1) continue;
        float4 x = acc[r];
        x.x = silu_f(x.x + bb.x);
        x.y = silu_f(x.y + bb.y);
        x.z = silu_f(x.z + bb.z);
        x.w = silu_f(x.w + bb.w);
        ho[(size_t)gr * 64 + cg] = x;
    }
}

extern "C" void kernel_launch(void* const* d_in, const int* in_sizes, int n_in,
                              void* d_out, int out_size, void* d_ws, size_t ws_size,
                              hipStream_t stream) {
    const float* feat = (const float*)d_in[0];
    const int* c2a = (const int*)d_in[1];
    const int* c2b = (const int*)d_in[2];
    const int* c3a = (const int*)d_in[3];
    const int* c3b = (const int*)d_in[4];
    const int* c4a = (const int*)d_in[5];
    const int* c4b = (const int*)d_in[6];
    const float* W = (const float*)d_in[7];
    const float* bias = (const float*)d_in[8];

    const int N1 = in_sizes[0] / DD;
    const int N2 = in_sizes[1];
    const int N3 = in_sizes[3];
    const int N4 = in_sizes[5];
    float* out = (float*)d_out;

    const size_t szh1 = (size_t)N1 * DD * sizeof(float);
    const size_t szh2 = (size_t)N2 * DD * sizeof(float);
    const size_t szh3 = (size_t)N3 * DD * sizeof(float);
    char* ws = (char*)d_ws;

    dim3 blk(256);
    auto rows_grid = [](int n) { return dim3((unsigned)((n + 3) / 4)); };

    // h1 accumulator lives in d_out; initialize with feat before any atomics
    hipMemcpyAsync(out, feat, szh1, hipMemcpyDeviceToDevice, stream);

    if (ws_size >= szh2 + szh3) {
        // Plan H2: materialized h2 + full acc3
        float* h2 = (float*)ws;
        float* acc3 = (float*)(ws + szh2);
        k_h2<<<rows_grid(N2), blk, 0, stream>>>(feat, c2a, c2b, h2, N2);
        hipMemsetAsync(acc3, 0, szh3, stream);
        k_up4_h2<<<rows_grid(N4), blk, 0, stream>>>(h2, c3a, c3b, c4a, c4b, acc3, N4);
        k_down3_h2<<<rows_grid(N3), blk, 0, stream>>>(h2, acc3, c2a, c2b, c3a, c3b, out, N3);
        k_down2_h2<<<rows_grid(N2), blk, 0, stream>>>(h2, c2a, c2b, out, N2);
    } else {
        // Plan FEAT: acc3 only, possibly chunked by destination range
        float* acc3 = (float*)ws;
        size_t chunk_rows = ws_size / ((size_t)DD * sizeof(float));
        if (chunk_rows > (size_t)N3) chunk_rows = (size_t)N3;
        if (chunk_rows == 0) chunk_rows = 1;  // degenerate guard
        for (int lo = 0; lo < N3; lo += (int)chunk_rows) {
            int hi = lo + (int)chunk_rows;
            if (hi > N3) hi = N3;
            hipMemsetAsync(acc3, 0, (size_t)(hi - lo) * DD * sizeof(float), stream);
            k_up4_feat<<<rows_grid(N4), blk, 0, stream>>>(feat, c2a, c2b, c3a, c3b,
                                                          c4a, c4b, acc3, N4, lo, hi);
            k_down3_feat<<<rows_grid(hi - lo), blk, 0, stream>>>(feat, acc3, c2a, c2b,
                                                                 c3a, c3b, out, lo, hi);
        }
        k_down2_feat<<<rows_grid(N2), blk, 0, stream>>>(feat, c2a, c2b, out, N2);
    }

    // out = silu(out @ W + b), in-place
    k_gemm_silu<<<dim3((unsigned)((N1 + 31) / 32)), blk, 0, stream>>>(out, W, bias, N1);
}

// Round 3
// 1004.786 us; speedup vs baseline: 5.4923x; 5.4923x over previous
//
#include <hip/hip_runtime.h>
#include <cstdint>
#include <cstddef>

#define DD 256   // feature dim
#define SCAN_BLK 256
#define SCAN_ELEMS 2048  // 8 per thread

// ---------- helpers --------------------------------------------------------
__device__ __forceinline__ float4 ldrow(const float* __restrict__ base, int row, int lane) {
    return ((const float4*)(base + (size_t)row * DD))[lane];
}
__device__ __forceinline__ float4 mul4(float4 a, float4 b) {
    return make_float4(a.x * b.x, a.y * b.y, a.z * b.z, a.w * b.w);
}
__device__ __forceinline__ float4 add4(float4 a, float4 b) {
    return make_float4(a.x + b.x, a.y + b.y, a.z + b.z, a.w + b.w);
}
__device__ __forceinline__ void atomic_add4(float* p, float4 v) {
    unsafeAtomicAdd(p + 0, v.x);
    unsafeAtomicAdd(p + 1, v.y);
    unsafeAtomicAdd(p + 2, v.z);
    unsafeAtomicAdd(p + 3, v.w);
}

// ================= CSR build (int atomics only) ============================
__global__ void k_count_pairs(const int* __restrict__ ea, const int* __restrict__ eb,
                              int ne, int* __restrict__ cnt) {
    int e = blockIdx.x * blockDim.x + threadIdx.x;
    if (e >= ne) return;
    atomicAdd(&cnt[ea[e]], 1);
    atomicAdd(&cnt[eb[e]], 1);
}

// mode 0: store edge id; mode 1: store other endpoint
__global__ void k_fill_pairs(const int* __restrict__ ea, const int* __restrict__ eb,
                             int ne, int* __restrict__ cursor, int* __restrict__ ent,
                             int mode) {
    int e = blockIdx.x * blockDim.x + threadIdx.x;
    if (e >= ne) return;
    int a = ea[e], b = eb[e];
    int pa = atomicAdd(&cursor[a], 1);
    int pb = atomicAdd(&cursor[b], 1);
    if (mode == 0) { ent[pa] = e; ent[pb] = e; }
    else           { ent[pa] = b; ent[pb] = a; }
}

__global__ void k_block_sums(const int* __restrict__ cnt, int n, int* __restrict__ bsum) {
    __shared__ int sdata[SCAN_BLK];
    int base = blockIdx.x * SCAN_ELEMS;
    int s = 0;
#pragma unroll
    for (int k = 0; k < 8; ++k) {
        int idx = base + threadIdx.x + k * SCAN_BLK;
        if (idx < n) s += cnt[idx];
    }
    sdata[threadIdx.x] = s;
    __syncthreads();
    for (int off = SCAN_BLK / 2; off > 0; off >>= 1) {
        if (threadIdx.x < off) sdata[threadIdx.x] += sdata[threadIdx.x + off];
        __syncthreads();
    }
    if (threadIdx.x == 0) bsum[blockIdx.x] = sdata[0];
}

__global__ void k_scan_bsums(int* __restrict__ bsum, int nb, int* __restrict__ total_out) {
    if (threadIdx.x == 0 && blockIdx.x == 0) {
        int acc = 0;
        for (int b = 0; b < nb; ++b) { int v = bsum[b]; bsum[b] = acc; acc += v; }
        *total_out = acc;
    }
}

__global__ void k_scan_final(const int* __restrict__ cnt, int n,
                             const int* __restrict__ bsum, int* __restrict__ offs) {
    __shared__ int sdata[SCAN_BLK];
    int base = blockIdx.x * SCAN_ELEMS;
    int t0 = base + threadIdx.x * 8;
    int loc[8];
    int s = 0;
#pragma unroll
    for (int k = 0; k < 8; ++k) {
        int idx = t0 + k;
        int v = (idx < n) ? cnt[idx] : 0;
        loc[k] = s;
        s += v;
    }
    sdata[threadIdx.x] = s;
    __syncthreads();
    int run = s;
    for (int off = 1; off < SCAN_BLK; off <<= 1) {
        int add = (threadIdx.x >= (unsigned)off) ? sdata[threadIdx.x - off] : 0;
        __syncthreads();
        run += add;
        sdata[threadIdx.x] = run;
        __syncthreads();
    }
    int texcl = run - s + bsum[blockIdx.x];
#pragma unroll
    for (int k = 0; k < 8; ++k) {
        int idx = t0 + k;
        if (idx < n) offs[idx] = texcl + loc[k];
    }
}

// ================= gather-based sweeps =====================================
// h3tot[j] = h3[j] * (1 + sum_{p incident} h3[other(p,j)]),
// h3[x] recomputed from feat via 4 gathers (feat is L3-resident)
__global__ void k_h3tot(const float* __restrict__ feat,
                        const int* __restrict__ c2a, const int* __restrict__ c2b,
                        const int* __restrict__ c3a, const int* __restrict__ c3b,
                        const int* __restrict__ offs4, const int* __restrict__ ent4,
                        float* __restrict__ h3tot, int n3) {
    int j = blockIdx.x * 4 + (threadIdx.x >> 6);
    int lane = threadIdx.x & 63;
    if (j >= n3) return;
    int q1 = c3a[j], q2 = c3b[j];
    float4 own = mul4(mul4(ldrow(feat, c2a[q1], lane), ldrow(feat, c2b[q1], lane)),
                      mul4(ldrow(feat, c2a[q2], lane), ldrow(feat, c2b[q2], lane)));
    float4 s = make_float4(0.f, 0.f, 0.f, 0.f);
    int e0 = offs4[j], e1 = offs4[j + 1];
    for (int e = e0; e < e1; ++e) {
        int o = ent4[e];
        int p1 = c3a[o], p2 = c3b[o];
        float4 ho = mul4(mul4(ldrow(feat, c2a[p1], lane), ldrow(feat, c2b[p1], lane)),
                         mul4(ldrow(feat, c2a[p2], lane), ldrow(feat, c2b[p2], lane)));
        s = add4(s, ho);
    }
    float4 r = mul4(own, make_float4(1.f + s.x, 1.f + s.y, 1.f + s.z, 1.f + s.w));
    ((float4*)(h3tot + (size_t)j * DD))[lane] = r;
}

// h1[i] = feat[i] + sum_{q incident} ( h2[q] + sum_{j incident to q} h3tot[j] )
__global__ void k_h1(const float* __restrict__ feat,
                     const int* __restrict__ c2a, const int* __restrict__ c2b,
                     const int* __restrict__ offs3, const int* __restrict__ ent3,
                     const int* __restrict__ offs2, const int* __restrict__ ent2,
                     const float* __restrict__ h3tot, float* __restrict__ out, int n1) {
    int i = blockIdx.x * 4 + (threadIdx.x >> 6);
    int lane = threadIdx.x & 63;
    if (i >= n1) return;
    float4 h = ldrow(feat, i, lane);
    int e0 = offs2[i], e1 = offs2[i + 1];
    for (int e = e0; e < e1; ++e) {
        int q = ent2[e];
        float4 acc = mul4(ldrow(feat, c2a[q], lane), ldrow(feat, c2b[q], lane));
        int f0 = offs3[q], f1 = offs3[q + 1];
        for (int f = f0; f < f1; ++f)
            acc = add4(acc, ldrow(h3tot, ent3[f], lane));
        h = add4(h, acc);
    }
    ((float4*)(out + (size_t)i * DD))[lane] = h;
}

// ================= fallback atomic-scatter kernels (round-2, passing) ======
__global__ void k_up4_feat(const float* __restrict__ feat,
                           const int* __restrict__ c2a, const int* __restrict__ c2b,
                           const int* __restrict__ c3a, const int* __restrict__ c3b,
                           const int* __restrict__ c4a, const int* __restrict__ c4b,
                           float* __restrict__ acc3, int n4, int lo, int hi) {
    int p = blockIdx.x * 4 + (threadIdx.x >> 6);
    int lane = threadIdx.x & 63;
    if (p >= n4) return;
    int j1 = c4a[p], j2 = c4b[p];
    bool in1 = (j1 >= lo && j1 < hi), in2 = (j2 >= lo && j2 < hi);
    if (!in1 && !in2) return;
    int q11 = c3a[j1], q12 = c3b[j1], q21 = c3a[j2], q22 = c3b[j2];
    float4 h2a = mul4(ldrow(feat, c2a[q11], lane), ldrow(feat, c2b[q11], lane));
    float4 h2b = mul4(ldrow(feat, c2a[q12], lane), ldrow(feat, c2b[q12], lane));
    float4 h2c = mul4(ldrow(feat, c2a[q21], lane), ldrow(feat, c2b[q21], lane));
    float4 h2d = mul4(ldrow(feat, c2a[q22], lane), ldrow(feat, c2b[q22], lane));
    float4 v = mul4(mul4(h2a, h2b), mul4(h2c, h2d));
    if (in1) atomic_add4(acc3 + (size_t)(j1 - lo) * DD + lane * 4, v);
    if (in2) atomic_add4(acc3 + (size_t)(j2 - lo) * DD + lane * 4, v);
}

__global__ void k_down3_feat(const float* __restrict__ feat,
                             const float* __restrict__ acc3,
                             const int* __restrict__ c2a, const int* __restrict__ c2b,
                             const int* __restrict__ c3a, const int* __restrict__ c3b,
                             float* __restrict__ out, int lo, int hi) {
    int j = lo + blockIdx.x * 4 + (threadIdx.x >> 6);
    int lane = threadIdx.x & 63;
    if (j >= hi) return;
    int q1 = c3a[j], q2 = c3b[j];
    float4 h2a = mul4(ldrow(feat, c2a[q1], lane), ldrow(feat, c2b[q1], lane));
    float4 h2b = mul4(ldrow(feat, c2a[q2], lane), ldrow(feat, c2b[q2], lane));
    float4 v = add4(mul4(h2a, h2b), ldrow(acc3, j - lo, lane));
    int d0 = c2a[q1], d1 = c2b[q1], d2 = c2a[q2], d3 = c2b[q2];
    atomic_add4(out + (size_t)d0 * DD + lane * 4, v);
    atomic_add4(out + (size_t)d1 * DD + lane * 4, v);
    atomic_add4(out + (size_t)d2 * DD + lane * 4, v);
    atomic_add4(out + (size_t)d3 * DD + lane * 4, v);
}

__global__ void k_down2_feat(const float* __restrict__ feat,
                             const int* __restrict__ c2a, const int* __restrict__ c2b,
                             float* __restrict__ out, int n2) {
    int q = blockIdx.x * 4 + (threadIdx.x >> 6);
    int lane = threadIdx.x & 63;
    if (q >= n2) return;
    int ra = c2a[q], rb = c2b[q];
    float4 v = mul4(ldrow(feat, ra, lane), ldrow(feat, rb, lane));
    atomic_add4(out + (size_t)ra * DD + lane * 4, v);
    atomic_add4(out + (size_t)rb * DD + lane * 4, v);
}

// ================= GEMM + bias + SiLU, in-place on h [n1][256] =============
__device__ __forceinline__ float silu_f(float x) { return x / (1.0f + expf(-x)); }

__global__ __launch_bounds__(256) void k_gemm_silu(float* __restrict__ h,
                                                   const float* __restrict__ W,
                                                   const float* __restrict__ bias,
                                                   int n1) {
    __shared__ float As[32 * DD];  // 32 KB
    const int t = threadIdx.x;
    const int row0 = blockIdx.x * 32;

    const float4* hv = (const float4*)h;
    float4* As4 = (float4*)As;
#pragma unroll
    for (int i = 0; i < 8; ++i) {
        int idx = t + i * 256;
        int r = idx >> 6, c = idx & 63;
        int gr = row0 + r;
        float4 v = make_float4(0.f, 0.f, 0.f, 0.f);
        if (gr < n1) v = hv[(size_t)gr * 64 + c];
        As4[idx] = v;
    }
    __syncthreads();

    const int rg = t >> 6;
    const int cg = t & 63;
    const float4* Wv = (const float4*)W;

    float4 acc[8];
#pragma unroll
    for (int r = 0; r < 8; ++r) acc[r] = make_float4(0.f, 0.f, 0.f, 0.f);

    for (int k = 0; k < DD; k += 4) {
        float4 a[8];
#pragma unroll
        for (int r = 0; r < 8; ++r)
            a[r] = *(const float4*)&As[(rg * 8 + r) * DD + k];
#pragma unroll
        for (int kk = 0; kk < 4; ++kk) {
            float4 w = Wv[(size_t)(k + kk) * 64 + cg];
#pragma unroll
            for (int r = 0; r < 8; ++r) {
                float av = (kk == 0) ? a[r].x : (kk == 1) ? a[r].y
                         : (kk == 2) ? a[r].z : a[r].w;
                acc[r].x += av * w.x;
                acc[r].y += av * w.y;
                acc[r].z += av * w.z;
                acc[r].w += av * w.w;
            }
        }
    }

    float4 bb = ((const float4*)bias)[cg];
    float4* ho = (float4*)h;
#pragma unroll
    for (int r = 0; r < 8; ++r) {
        int gr = row0 + rg * 8 + r;
        if (gr >= n1) continue;
        float4 x = acc[r];
        x.x = silu_f(x.x + bb.x);
        x.y = silu_f(x.y + bb.y);
        x.z = silu_f(x.z + bb.z);
        x.w = silu_f(x.w + bb.w);
        ho[(size_t)gr * 64 + cg] = x;
    }
}

// ================= launcher ================================================
static inline size_t al16(size_t x) { return (x + 15) & ~(size_t)15; }

extern "C" void kernel_launch(void* const* d_in, const int* in_sizes, int n_in,
                              void* d_out, int out_size, void* d_ws, size_t ws_size,
                              hipStream_t stream) {
    const float* feat = (const float*)d_in[0];
    const int* c2a = (const int*)d_in[1];
    const int* c2b = (const int*)d_in[2];
    const int* c3a = (const int*)d_in[3];
    const int* c3b = (const int*)d_in[4];
    const int* c4a = (const int*)d_in[5];
    const int* c4b = (const int*)d_in[6];
    const float* W = (const float*)d_in[7];
    const float* bias = (const float*)d_in[8];

    const int N1 = in_sizes[0] / DD;
    const int N2 = in_sizes[1];
    const int N3 = in_sizes[3];
    const int N4 = in_sizes[5];
    float* out = (float*)d_out;
    char* ws = (char*)d_ws;

    dim3 blk(256);
    auto rows_grid = [](int n) { return dim3((unsigned)((n + 3) / 4)); };
    auto thr_grid = [](int n) { return dim3((unsigned)((n + 255) / 256)); };

    int maxN = N1 > N2 ? N1 : N2;
    if (N3 > maxN) maxN = N3;

    // gather-plan layout
    size_t cnt_b = al16((size_t)maxN * 4);
    size_t bsum_b = al16(1024);
    size_t offs4_b = al16((size_t)(N3 + 1) * 4);
    size_t ent4_b = al16((size_t)2 * N4 * 4);
    size_t offs3_b = al16((size_t)(N2 + 1) * 4);
    size_t ent3_b = al16((size_t)2 * N3 * 4);
    size_t offs2_b = al16((size_t)(N1 + 1) * 4);
    size_t ent2_b = al16((size_t)2 * N2 * 4);
    size_t h3_b = (size_t)N3 * DD * sizeof(float);
    size_t need = cnt_b + bsum_b + offs4_b + ent4_b + offs3_b + ent3_b +
                  offs2_b + ent2_b + h3_b;

    if (ws_size >= need) {
        char* p = ws;
        int* cnt = (int*)p;    p += cnt_b;
        int* bsum = (int*)p;   p += bsum_b;
        int* offs4 = (int*)p;  p += offs4_b;
        int* ent4 = (int*)p;   p += ent4_b;
        int* offs3 = (int*)p;  p += offs3_b;
        int* ent3 = (int*)p;   p += ent3_b;
        int* offs2 = (int*)p;  p += offs2_b;
        int* ent2 = (int*)p;   p += ent2_b;
        float* h3tot = (float*)p;

        auto build_csr = [&](const int* ea, const int* eb, int ne, int nnode,
                             int* offs, int* ent, int mode) {
            hipMemsetAsync(cnt, 0, (size_t)nnode * 4, stream);
            k_count_pairs<<<thr_grid(ne), blk, 0, stream>>>(ea, eb, ne, cnt);
            int nb = (nnode + SCAN_ELEMS - 1) / SCAN_ELEMS;
            k_block_sums<<<dim3((unsigned)nb), dim3(SCAN_BLK), 0, stream>>>(cnt, nnode, bsum);
            k_scan_bsums<<<dim3(1), dim3(64), 0, stream>>>(bsum, nb, offs + nnode);
            k_scan_final<<<dim3((unsigned)nb), dim3(SCAN_BLK), 0, stream>>>(cnt, nnode, bsum, offs);
            hipMemcpyAsync(cnt, offs, (size_t)nnode * 4, hipMemcpyDeviceToDevice, stream);
            k_fill_pairs<<<thr_grid(ne), blk, 0, stream>>>(ea, eb, ne, cnt, ent, mode);
        };

        build_csr(c4a, c4b, N4, N3, offs4, ent4, /*mode=other*/1);
        build_csr(c3a, c3b, N3, N2, offs3, ent3, /*mode=edge*/0);
        build_csr(c2a, c2b, N2, N1, offs2, ent2, /*mode=edge*/0);

        k_h3tot<<<rows_grid(N3), blk, 0, stream>>>(feat, c2a, c2b, c3a, c3b,
                                                   offs4, ent4, h3tot, N3);
        k_h1<<<rows_grid(N1), blk, 0, stream>>>(feat, c2a, c2b, offs3, ent3,
                                                offs2, ent2, h3tot, out, N1);
    } else {
        // fallback: round-2 atomic-scatter plan (chunked acc3)
        const size_t szh1 = (size_t)N1 * DD * sizeof(float);
        hipMemcpyAsync(out, feat, szh1, hipMemcpyDeviceToDevice, stream);
        float* acc3 = (float*)ws;
        size_t chunk_rows = ws_size / ((size_t)DD * sizeof(float));
        if (chunk_rows > (size_t)N3) chunk_rows = (size_t)N3;
        if (chunk_rows == 0) chunk_rows = 1;
        for (int lo = 0; lo < N3; lo += (int)chunk_rows) {
            int hi = lo + (int)chunk_rows;
            if (hi > N3) hi = N3;
            hipMemsetAsync(acc3, 0, (size_t)(hi - lo) * DD * sizeof(float), stream);
            k_up4_feat<<<rows_grid(N4), blk, 0, stream>>>(feat, c2a, c2b, c3a, c3b,
                                                          c4a, c4b, acc3, N4, lo, hi);
            k_down3_feat<<<rows_grid(hi - lo), blk, 0, stream>>>(feat, acc3, c2a, c2b,
                                                                 c3a, c3b, out, lo, hi);
        }
        k_down2_feat<<<rows_grid(N2), blk, 0, stream>>>(feat, c2a, c2b, out, N2);
    }

    // out = silu(out @ W + b), in-place
    k_gemm_silu<<<dim3((unsigned)((N1 + 31) / 32)), blk, 0, stream>>>(out, W, bias, N1);
}

// Round 4
// 902.525 us; speedup vs baseline: 6.1146x; 1.1133x over previous
//
#include <hip/hip_runtime.h>
#include <cstdint>
#include <cstddef>

#define DD 256   // feature dim
#define SCAN_BLK 256
#define SCAN_ELEMS 2048  // 8 per thread

// ---------- helpers --------------------------------------------------------
__device__ __forceinline__ float4 ldrow(const float* __restrict__ base, int row, int lane) {
    return ((const float4*)(base + (size_t)row * DD))[lane];
}
__device__ __forceinline__ float4 mul4(float4 a, float4 b) {
    return make_float4(a.x * b.x, a.y * b.y, a.z * b.z, a.w * b.w);
}
__device__ __forceinline__ float4 add4(float4 a, float4 b) {
    return make_float4(a.x + b.x, a.y + b.y, a.z + b.z, a.w + b.w);
}

// ================= CSR build (int atomics only) ============================
__global__ void k_count_pairs(const int* __restrict__ ea, const int* __restrict__ eb,
                              int ne, int* __restrict__ cnt) {
    int e = blockIdx.x * blockDim.x + threadIdx.x;
    if (e >= ne) return;
    atomicAdd(&cnt[ea[e]], 1);
    atomicAdd(&cnt[eb[e]], 1);
}

// mode 0: store edge id; mode 1: store other endpoint
__global__ void k_fill_pairs(const int* __restrict__ ea, const int* __restrict__ eb,
                             int ne, int* __restrict__ cursor, int* __restrict__ ent,
                             int mode) {
    int e = blockIdx.x * blockDim.x + threadIdx.x;
    if (e >= ne) return;
    int a = ea[e], b = eb[e];
    int pa = atomicAdd(&cursor[a], 1);
    int pb = atomicAdd(&cursor[b], 1);
    if (mode == 0) { ent[pa] = e; ent[pb] = e; }
    else           { ent[pa] = b; ent[pb] = a; }
}

__global__ void k_block_sums(const int* __restrict__ cnt, int n, int* __restrict__ bsum) {
    __shared__ int sdata[SCAN_BLK];
    int base = blockIdx.x * SCAN_ELEMS;
    int s = 0;
#pragma unroll
    for (int k = 0; k < 8; ++k) {
        int idx = base + threadIdx.x + k * SCAN_BLK;
        if (idx < n) s += cnt[idx];
    }
    sdata[threadIdx.x] = s;
    __syncthreads();
    for (int off = SCAN_BLK / 2; off > 0; off >>= 1) {
        if (threadIdx.x < off) sdata[threadIdx.x] += sdata[threadIdx.x + off];
        __syncthreads();
    }
    if (threadIdx.x == 0) bsum[blockIdx.x] = sdata[0];
}

__global__ void k_scan_bsums(int* __restrict__ bsum, int nb, int* __restrict__ total_out) {
    if (threadIdx.x == 0 && blockIdx.x == 0) {
        int acc = 0;
        for (int b = 0; b < nb; ++b) { int v = bsum[b]; bsum[b] = acc; acc += v; }
        *total_out = acc;
    }
}

__global__ void k_scan_final(const int* __restrict__ cnt, int n,
                             const int* __restrict__ bsum, int* __restrict__ offs) {
    __shared__ int sdata[SCAN_BLK];
    int base = blockIdx.x * SCAN_ELEMS;
    int t0 = base + threadIdx.x * 8;
    int loc[8];
    int s = 0;
#pragma unroll
    for (int k = 0; k < 8; ++k) {
        int idx = t0 + k;
        int v = (idx < n) ? cnt[idx] : 0;
        loc[k] = s;
        s += v;
    }
    sdata[threadIdx.x] = s;
    __syncthreads();
    int run = s;
    for (int off = 1; off < SCAN_BLK; off <<= 1) {
        int add = (threadIdx.x >= (unsigned)off) ? sdata[threadIdx.x - off] : 0;
        __syncthreads();
        run += add;
        sdata[threadIdx.x] = run;
        __syncthreads();
    }
    int texcl = run - s + bsum[blockIdx.x];
#pragma unroll
    for (int k = 0; k < 8; ++k) {
        int idx = t0 + k;
        if (idx < n) offs[idx] = texcl + loc[k];
    }
}

// ================= h2 materialization ======================================
__global__ void k_h2(const float* __restrict__ feat, const int* __restrict__ c2a,
                     const int* __restrict__ c2b, float* __restrict__ h2, int n2) {
    int q = blockIdx.x * 4 + (threadIdx.x >> 6);
    int lane = threadIdx.x & 63;
    if (q >= n2) return;
    float4 v = mul4(ldrow(feat, c2a[q], lane), ldrow(feat, c2b[q], lane));
    ((float4*)(h2 + (size_t)q * DD))[lane] = v;
}

// ================= h3tot chunk (h2-backed) =================================
// h3tot[j] = h3[j] * (1 + sum_{p incident} h3[other(p,j)]), h3[x] = h2[c3a[x]]*h2[c3b[x]]
__global__ void k_h3tot_h2(const float* __restrict__ h2,
                           const int* __restrict__ c3a, const int* __restrict__ c3b,
                           const int* __restrict__ offs4, const int* __restrict__ ent4,
                           float* __restrict__ h3chunk, int lo, int hi) {
    int j = lo + blockIdx.x * 4 + (threadIdx.x >> 6);
    int lane = threadIdx.x & 63;
    if (j >= hi) return;
    float4 own = mul4(ldrow(h2, c3a[j], lane), ldrow(h2, c3b[j], lane));
    float4 s = make_float4(0.f, 0.f, 0.f, 0.f);
    int e0 = offs4[j], e1 = offs4[j + 1];
    for (int e = e0; e < e1; ++e) {
        int o = ent4[e];
        s = add4(s, mul4(ldrow(h2, c3a[o], lane), ldrow(h2, c3b[o], lane)));
    }
    float4 r = mul4(own, make_float4(1.f + s.x, 1.f + s.y, 1.f + s.z, 1.f + s.w));
    ((float4*)(h3chunk + (size_t)(j - lo) * DD))[lane] = r;
}

// ================= h1 accumulation pass (per chunk) ========================
// first: out[i] = feat[i] + sum_q h2[q] + sum_{j in chunk} h3tot[j]
// else : out[i] += sum_{j in chunk} h3tot[j]
__global__ void k_h1_pass(const float* __restrict__ feat,
                          const float* __restrict__ h2,
                          const int* __restrict__ offs3, const int* __restrict__ ent3,
                          const int* __restrict__ offs2, const int* __restrict__ ent2,
                          const float* __restrict__ h3chunk,
                          float* __restrict__ out, int n1, int lo, int hi, int first) {
    int i = blockIdx.x * 4 + (threadIdx.x >> 6);
    int lane = threadIdx.x & 63;
    if (i >= n1) return;
    float4 h = first ? ldrow(feat, i, lane) : ldrow(out, i, lane);
    int e0 = offs2[i], e1 = offs2[i + 1];
    for (int e = e0; e < e1; ++e) {
        int q = ent2[e];
        if (first) h = add4(h, ldrow(h2, q, lane));
        int f0 = offs3[q], f1 = offs3[q + 1];
        for (int f = f0; f < f1; ++f) {
            int j = ent3[f];
            if (j >= lo && j < hi)
                h = add4(h, ldrow(h3chunk, j - lo, lane));
        }
    }
    ((float4*)(out + (size_t)i * DD))[lane] = h;
}

// ================= fallback (round-3 verified path) ========================
__global__ void k_h3tot_feat(const float* __restrict__ feat,
                             const int* __restrict__ c2a, const int* __restrict__ c2b,
                             const int* __restrict__ c3a, const int* __restrict__ c3b,
                             const int* __restrict__ offs4, const int* __restrict__ ent4,
                             float* __restrict__ h3tot, int n3) {
    int j = blockIdx.x * 4 + (threadIdx.x >> 6);
    int lane = threadIdx.x & 63;
    if (j >= n3) return;
    int q1 = c3a[j], q2 = c3b[j];
    float4 own = mul4(mul4(ldrow(feat, c2a[q1], lane), ldrow(feat, c2b[q1], lane)),
                      mul4(ldrow(feat, c2a[q2], lane), ldrow(feat, c2b[q2], lane)));
    float4 s = make_float4(0.f, 0.f, 0.f, 0.f);
    int e0 = offs4[j], e1 = offs4[j + 1];
    for (int e = e0; e < e1; ++e) {
        int o = ent4[e];
        int p1 = c3a[o], p2 = c3b[o];
        float4 ho = mul4(mul4(ldrow(feat, c2a[p1], lane), ldrow(feat, c2b[p1], lane)),
                         mul4(ldrow(feat, c2a[p2], lane), ldrow(feat, c2b[p2], lane)));
        s = add4(s, ho);
    }
    float4 r = mul4(own, make_float4(1.f + s.x, 1.f + s.y, 1.f + s.z, 1.f + s.w));
    ((float4*)(h3tot + (size_t)j * DD))[lane] = r;
}

__global__ void k_h1_feat(const float* __restrict__ feat,
                          const int* __restrict__ c2a, const int* __restrict__ c2b,
                          const int* __restrict__ offs3, const int* __restrict__ ent3,
                          const int* __restrict__ offs2, const int* __restrict__ ent2,
                          const float* __restrict__ h3tot, float* __restrict__ out, int n1) {
    int i = blockIdx.x * 4 + (threadIdx.x >> 6);
    int lane = threadIdx.x & 63;
    if (i >= n1) return;
    float4 h = ldrow(feat, i, lane);
    int e0 = offs2[i], e1 = offs2[i + 1];
    for (int e = e0; e < e1; ++e) {
        int q = ent2[e];
        float4 acc = mul4(ldrow(feat, c2a[q], lane), ldrow(feat, c2b[q], lane));
        int f0 = offs3[q], f1 = offs3[q + 1];
        for (int f = f0; f < f1; ++f)
            acc = add4(acc, ldrow(h3tot, ent3[f], lane));
        h = add4(h, acc);
    }
    ((float4*)(out + (size_t)i * DD))[lane] = h;
}

// ================= GEMM + bias + SiLU, in-place on h [n1][256] =============
__device__ __forceinline__ float silu_f(float x) { return x / (1.0f + expf(-x)); }

__global__ __launch_bounds__(256) void k_gemm_silu(float* __restrict__ h,
                                                   const float* __restrict__ W,
                                                   const float* __restrict__ bias,
                                                   int n1) {
    __shared__ float As[32 * DD];  // 32 KB
    const int t = threadIdx.x;
    const int row0 = blockIdx.x * 32;

    const float4* hv = (const float4*)h;
    float4* As4 = (float4*)As;
#pragma unroll
    for (int i = 0; i < 8; ++i) {
        int idx = t + i * 256;
        int r = idx >> 6, c = idx & 63;
        int gr = row0 + r;
        float4 v = make_float4(0.f, 0.f, 0.f, 0.f);
        if (gr < n1) v = hv[(size_t)gr * 64 + c];
        As4[idx] = v;
    }
    __syncthreads();

    const int rg = t >> 6;
    const int cg = t & 63;
    const float4* Wv = (const float4*)W;

    float4 acc[8];
#pragma unroll
    for (int r = 0; r < 8; ++r) acc[r] = make_float4(0.f, 0.f, 0.f, 0.f);

    for (int k = 0; k < DD; k += 4) {
        float4 a[8];
#pragma unroll
        for (int r = 0; r < 8; ++r)
            a[r] = *(const float4*)&As[(rg * 8 + r) * DD + k];
#pragma unroll
        for (int kk = 0; kk < 4; ++kk) {
            float4 w = Wv[(size_t)(k + kk) * 64 + cg];
#pragma unroll
            for (int r = 0; r < 8; ++r) {
                float av = (kk == 0) ? a[r].x : (kk == 1) ? a[r].y
                         : (kk == 2) ? a[r].z : a[r].w;
                acc[r].x += av * w.x;
                acc[r].y += av * w.y;
                acc[r].z += av * w.z;
                acc[r].w += av * w.w;
            }
        }
    }

    float4 bb = ((const float4*)bias)[cg];
    float4* ho = (float4*)h;
#pragma unroll
    for (int r = 0; r < 8; ++r) {
        int gr = row0 + rg * 8 + r;
        if (gr >= n1) continue;
        float4 x = acc[r];
        x.x = silu_f(x.x + bb.x);
        x.y = silu_f(x.y + bb.y);
        x.z = silu_f(x.z + bb.z);
        x.w = silu_f(x.w + bb.w);
        ho[(size_t)gr * 64 + cg] = x;
    }
}

// ================= launcher ================================================
static inline size_t al16(size_t x) { return (x + 15) & ~(size_t)15; }

extern "C" void kernel_launch(void* const* d_in, const int* in_sizes, int n_in,
                              void* d_out, int out_size, void* d_ws, size_t ws_size,
                              hipStream_t stream) {
    const float* feat = (const float*)d_in[0];
    const int* c2a = (const int*)d_in[1];
    const int* c2b = (const int*)d_in[2];
    const int* c3a = (const int*)d_in[3];
    const int* c3b = (const int*)d_in[4];
    const int* c4a = (const int*)d_in[5];
    const int* c4b = (const int*)d_in[6];
    const float* W = (const float*)d_in[7];
    const float* bias = (const float*)d_in[8];

    const int N1 = in_sizes[0] / DD;
    const int N2 = in_sizes[1];
    const int N3 = in_sizes[3];
    const int N4 = in_sizes[5];
    float* out = (float*)d_out;
    char* ws = (char*)d_ws;

    dim3 blk(256);
    auto rows_grid = [](int n) { return dim3((unsigned)((n + 3) / 4)); };
    auto thr_grid = [](int n) { return dim3((unsigned)((n + 255) / 256)); };

    int maxN = N1 > N2 ? N1 : N2;
    if (N3 > maxN) maxN = N3;

    // CSR scratch layout (shared by both plans)
    size_t cnt_b = al16((size_t)maxN * 4);
    size_t bsum_b = al16(1024);
    size_t offs4_b = al16((size_t)(N3 + 1) * 4);
    size_t ent4_b = al16((size_t)2 * N4 * 4);
    size_t offs3_b = al16((size_t)(N2 + 1) * 4);
    size_t ent3_b = al16((size_t)2 * N3 * 4);
    size_t offs2_b = al16((size_t)(N1 + 1) * 4);
    size_t ent2_b = al16((size_t)2 * N2 * 4);
    size_t csr_b = cnt_b + bsum_b + offs4_b + ent4_b + offs3_b + ent3_b +
                   offs2_b + ent2_b;
    size_t h2_b = (size_t)N2 * DD * sizeof(float);
    size_t h3_b = (size_t)N3 * DD * sizeof(float);

    char* p = ws;
    int* cnt = (int*)p;    p += cnt_b;
    int* bsum = (int*)p;   p += bsum_b;
    int* offs4 = (int*)p;  p += offs4_b;
    int* ent4 = (int*)p;   p += ent4_b;
    int* offs3 = (int*)p;  p += offs3_b;
    int* ent3 = (int*)p;   p += ent3_b;
    int* offs2 = (int*)p;  p += offs2_b;
    int* ent2 = (int*)p;   p += ent2_b;
    char* dyn = p;  // remaining: ws_size - csr_b bytes

    auto build_csr = [&](const int* ea, const int* eb, int ne, int nnode,
                         int* offs, int* ent, int mode) {
        hipMemsetAsync(cnt, 0, (size_t)nnode * 4, stream);
        k_count_pairs<<<thr_grid(ne), blk, 0, stream>>>(ea, eb, ne, cnt);
        int nb = (nnode + SCAN_ELEMS - 1) / SCAN_ELEMS;
        k_block_sums<<<dim3((unsigned)nb), dim3(SCAN_BLK), 0, stream>>>(cnt, nnode, bsum);
        k_scan_bsums<<<dim3(1), dim3(64), 0, stream>>>(bsum, nb, offs + nnode);
        k_scan_final<<<dim3((unsigned)nb), dim3(SCAN_BLK), 0, stream>>>(cnt, nnode, bsum, offs);
        hipMemcpyAsync(cnt, offs, (size_t)nnode * 4, hipMemcpyDeviceToDevice, stream);
        k_fill_pairs<<<thr_grid(ne), blk, 0, stream>>>(ea, eb, ne, cnt, ent, mode);
    };

    size_t free_after_h2 = (ws_size > csr_b + h2_b) ? ws_size - csr_b - h2_b : 0;
    int chunk_rows = (int)(free_after_h2 / ((size_t)DD * sizeof(float)));
    if (chunk_rows > N3) chunk_rows = N3;

    if (chunk_rows >= 25000) {
        // ===== h2-backed chunked plan =====
        float* h2 = (float*)dyn;
        float* h3chunk = (float*)(dyn + h2_b);

        build_csr(c4a, c4b, N4, N3, offs4, ent4, /*mode=other*/1);
        build_csr(c3a, c3b, N3, N2, offs3, ent3, /*mode=edge*/0);
        build_csr(c2a, c2b, N2, N1, offs2, ent2, /*mode=edge*/0);

        k_h2<<<rows_grid(N2), blk, 0, stream>>>(feat, c2a, c2b, h2, N2);

        int first = 1;
        for (int lo = 0; lo < N3; lo += chunk_rows) {
            int hi = lo + chunk_rows;
            if (hi > N3) hi = N3;
            k_h3tot_h2<<<rows_grid(hi - lo), blk, 0, stream>>>(h2, c3a, c3b,
                                                               offs4, ent4,
                                                               h3chunk, lo, hi);
            k_h1_pass<<<rows_grid(N1), blk, 0, stream>>>(feat, h2, offs3, ent3,
                                                         offs2, ent2, h3chunk,
                                                         out, N1, lo, hi, first);
            first = 0;
        }
    } else if (ws_size >= csr_b + h3_b) {
        // ===== round-3 verified fallback =====
        float* h3tot = (float*)dyn;
        build_csr(c4a, c4b, N4, N3, offs4, ent4, 1);
        build_csr(c3a, c3b, N3, N2, offs3, ent3, 0);
        build_csr(c2a, c2b, N2, N1, offs2, ent2, 0);
        k_h3tot_feat<<<rows_grid(N3), blk, 0, stream>>>(feat, c2a, c2b, c3a, c3b,
                                                        offs4, ent4, h3tot, N3);
        k_h1_feat<<<rows_grid(N1), blk, 0, stream>>>(feat, c2a, c2b, offs3, ent3,
                                                     offs2, ent2, h3tot, out, N1);
    }

    // out = silu(out @ W + b), in-place
    k_gemm_silu<<<dim3((unsigned)((N1 + 31) / 32)), blk, 0, stream>>>(out, W, bias, N1);
}

// Round 5
// 856.986 us; speedup vs baseline: 6.4395x; 1.0531x over previous
//
#include <hip/hip_runtime.h>
#include <cstdint>
#include <cstddef>

#define DD 256   // feature dim
#define SCAN_BLK 256
#define SCAN_ELEMS 2048  // 8 per thread

// ---------- helpers --------------------------------------------------------
__device__ __forceinline__ float4 ldrow(const float* __restrict__ base, int row, int lane) {
    return ((const float4*)(base + (size_t)row * DD))[lane];
}
__device__ __forceinline__ float4 mul4(float4 a, float4 b) {
    return make_float4(a.x * b.x, a.y * b.y, a.z * b.z, a.w * b.w);
}
__device__ __forceinline__ float4 add4(float4 a, float4 b) {
    return make_float4(a.x + b.x, a.y + b.y, a.z + b.z, a.w + b.w);
}

// ================= CSR build (int atomics only) ============================
__global__ void k_count_pairs(const int* __restrict__ ea, const int* __restrict__ eb,
                              int ne, int* __restrict__ cnt) {
    int e = blockIdx.x * blockDim.x + threadIdx.x;
    if (e >= ne) return;
    atomicAdd(&cnt[ea[e]], 1);
    atomicAdd(&cnt[eb[e]], 1);
}

// store level-3 edge id per q incidence
__global__ void k_fill_edges(const int* __restrict__ ea, const int* __restrict__ eb,
                             int ne, int* __restrict__ cursor, int* __restrict__ ent) {
    int e = blockIdx.x * blockDim.x + threadIdx.x;
    if (e >= ne) return;
    int a = ea[e], b = eb[e];
    int pa = atomicAdd(&cursor[a], 1);
    int pb = atomicAdd(&cursor[b], 1);
    ent[pa] = e;
    ent[pb] = e;
}

// level-4 incidence: store the OTHER endpoint's (c3a,c3b) pair directly
__global__ void k_fill_pairs4(const int* __restrict__ c4a, const int* __restrict__ c4b,
                              const int* __restrict__ c3a, const int* __restrict__ c3b,
                              int ne, int* __restrict__ cursor, int2* __restrict__ entp) {
    int e = blockIdx.x * blockDim.x + threadIdx.x;
    if (e >= ne) return;
    int a = c4a[e], b = c4b[e];
    int2 prA = make_int2(c3a[b], c3b[b]);  // stored at a's slot: other = b
    int2 prB = make_int2(c3a[a], c3b[a]);  // stored at b's slot: other = a
    int pa = atomicAdd(&cursor[a], 1);
    int pb = atomicAdd(&cursor[b], 1);
    entp[pa] = prA;
    entp[pb] = prB;
}

__global__ void k_block_sums(const int* __restrict__ cnt, int n, int* __restrict__ bsum) {
    __shared__ int sdata[SCAN_BLK];
    int base = blockIdx.x * SCAN_ELEMS;
    int s = 0;
#pragma unroll
    for (int k = 0; k < 8; ++k) {
        int idx = base + threadIdx.x + k * SCAN_BLK;
        if (idx < n) s += cnt[idx];
    }
    sdata[threadIdx.x] = s;
    __syncthreads();
    for (int off = SCAN_BLK / 2; off > 0; off >>= 1) {
        if (threadIdx.x < off) sdata[threadIdx.x] += sdata[threadIdx.x + off];
        __syncthreads();
    }
    if (threadIdx.x == 0) bsum[blockIdx.x] = sdata[0];
}

__global__ void k_scan_bsums(int* __restrict__ bsum, int nb, int* __restrict__ total_out) {
    if (threadIdx.x == 0 && blockIdx.x == 0) {
        int acc = 0;
        for (int b = 0; b < nb; ++b) { int v = bsum[b]; bsum[b] = acc; acc += v; }
        *total_out = acc;
    }
}

__global__ void k_scan_final(const int* __restrict__ cnt, int n,
                             const int* __restrict__ bsum, int* __restrict__ offs) {
    __shared__ int sdata[SCAN_BLK];
    int base = blockIdx.x * SCAN_ELEMS;
    int t0 = base + threadIdx.x * 8;
    int loc[8];
    int s = 0;
#pragma unroll
    for (int k = 0; k < 8; ++k) {
        int idx = t0 + k;
        int v = (idx < n) ? cnt[idx] : 0;
        loc[k] = s;
        s += v;
    }
    sdata[threadIdx.x] = s;
    __syncthreads();
    int run = s;
    for (int off = 1; off < SCAN_BLK; off <<= 1) {
        int add = (threadIdx.x >= (unsigned)off) ? sdata[threadIdx.x - off] : 0;
        __syncthreads();
        run += add;
        sdata[threadIdx.x] = run;
        __syncthreads();
    }
    int texcl = run - s + bsum[blockIdx.x];
#pragma unroll
    for (int k = 0; k < 8; ++k) {
        int idx = t0 + k;
        if (idx < n) offs[idx] = texcl + loc[k];
    }
}

// ========== flat i -> {level-3 edge} list (composition of CSR2 and CSR3) ===
__global__ void k_flat_cnt(const int* __restrict__ offs2, const int* __restrict__ ent2,
                           const int* __restrict__ offs3, int n1, int* __restrict__ cntF) {
    int i = blockIdx.x * blockDim.x + threadIdx.x;
    if (i >= n1) return;
    int c = 0;
    int e0 = offs2[i], e1 = offs2[i + 1];
    for (int e = e0; e < e1; ++e) {
        int q = ent2[e];
        c += offs3[q + 1] - offs3[q];
    }
    cntF[i] = c;
}

__global__ void k_flat_fill(const int* __restrict__ offs2, const int* __restrict__ ent2,
                            const int* __restrict__ offs3, const int* __restrict__ ent3,
                            const int* __restrict__ offsF, int n1, int* __restrict__ entF) {
    int i = blockIdx.x * blockDim.x + threadIdx.x;
    if (i >= n1) return;
    int pos = offsF[i];
    int e0 = offs2[i], e1 = offs2[i + 1];
    for (int e = e0; e < e1; ++e) {
        int q = ent2[e];
        int f0 = offs3[q], f1 = offs3[q + 1];
        for (int f = f0; f < f1; ++f) entF[pos++] = ent3[f];
    }
}

// ================= h2 materialization ======================================
__global__ void k_h2(const float* __restrict__ feat, const int* __restrict__ c2a,
                     const int* __restrict__ c2b, float* __restrict__ h2, int n2) {
    int q = blockIdx.x * 4 + (threadIdx.x >> 6);
    int lane = threadIdx.x & 63;
    if (q >= n2) return;
    float4 v = mul4(ldrow(feat, c2a[q], lane), ldrow(feat, c2b[q], lane));
    ((float4*)(h2 + (size_t)q * DD))[lane] = v;
}

// ============ out init: out[i] = feat[i] + sum_{q inc i} h2[q] =============
__global__ void k_out_init(const float* __restrict__ feat, const float* __restrict__ h2,
                           const int* __restrict__ offs2, const int* __restrict__ ent2,
                           float* __restrict__ out, int n1) {
    int i = blockIdx.x * 4 + (threadIdx.x >> 6);
    int lane = threadIdx.x & 63;
    if (i >= n1) return;
    float4 h = ldrow(feat, i, lane);
    int e0 = offs2[i], e1 = offs2[i + 1];
    int e = e0;
    for (; e + 1 < e1; e += 2) {
        int q0 = ent2[e], q1 = ent2[e + 1];
        float4 v0 = ldrow(h2, q0, lane), v1 = ldrow(h2, q1, lane);
        h = add4(h, add4(v0, v1));
    }
    if (e < e1) h = add4(h, ldrow(h2, ent2[e], lane));
    ((float4*)(out + (size_t)i * DD))[lane] = h;
}

// ================= h3tot chunk (h2-backed, pair list) ======================
// h3tot[j] = own * (1 + sum_e h2[p.x]*h2[p.y]); own = h2[c3a[j]]*h2[c3b[j]]
__global__ void k_h3tot_h2(const float* __restrict__ h2,
                           const int* __restrict__ c3a, const int* __restrict__ c3b,
                           const int* __restrict__ offs4, const int2* __restrict__ entp,
                           float* __restrict__ h3chunk, int lo, int hi) {
    int j = lo + blockIdx.x * 4 + (threadIdx.x >> 6);
    int lane = threadIdx.x & 63;
    if (j >= hi) return;
    float4 own = mul4(ldrow(h2, c3a[j], lane), ldrow(h2, c3b[j], lane));
    float4 s = make_float4(0.f, 0.f, 0.f, 0.f);
    int e0 = offs4[j], e1 = offs4[j + 1];
    int e = e0;
    for (; e + 1 < e1; e += 2) {
        int2 p0 = entp[e], p1 = entp[e + 1];
        float4 a0 = ldrow(h2, p0.x, lane), b0 = ldrow(h2, p0.y, lane);
        float4 a1 = ldrow(h2, p1.x, lane), b1 = ldrow(h2, p1.y, lane);
        s = add4(s, add4(mul4(a0, b0), mul4(a1, b1)));
    }
    if (e < e1) {
        int2 p = entp[e];
        s = add4(s, mul4(ldrow(h2, p.x, lane), ldrow(h2, p.y, lane)));
    }
    float4 r = mul4(own, make_float4(1.f + s.x, 1.f + s.y, 1.f + s.z, 1.f + s.w));
    ((float4*)(h3chunk + (size_t)(j - lo) * DD))[lane] = r;
}

// ============ h1 accumulation via flat list (per chunk, RMW out) ===========
__global__ void k_h1_flat(const int* __restrict__ offsF, const int* __restrict__ entF,
                          const float* __restrict__ h3chunk,
                          float* __restrict__ out, int n1, int lo, int hi) {
    int i = blockIdx.x * 4 + (threadIdx.x >> 6);
    int lane = threadIdx.x & 63;
    if (i >= n1) return;
    float4 h = ldrow(out, i, lane);
    int f0 = offsF[i], f1 = offsF[i + 1];
    int f = f0;
    for (; f + 1 < f1; f += 2) {
        int j0 = entF[f], j1 = entF[f + 1];
        bool in0 = (j0 >= lo) && (j0 < hi);
        bool in1 = (j1 >= lo) && (j1 < hi);
        if (in0 && in1) {
            float4 v0 = ldrow(h3chunk, j0 - lo, lane);
            float4 v1 = ldrow(h3chunk, j1 - lo, lane);
            h = add4(h, add4(v0, v1));
        } else if (in0) {
            h = add4(h, ldrow(h3chunk, j0 - lo, lane));
        } else if (in1) {
            h = add4(h, ldrow(h3chunk, j1 - lo, lane));
        }
    }
    if (f < f1) {
        int j0 = entF[f];
        if (j0 >= lo && j0 < hi) h = add4(h, ldrow(h3chunk, j0 - lo, lane));
    }
    ((float4*)(out + (size_t)i * DD))[lane] = h;
}

// ================= GEMM + bias + SiLU, in-place on h [n1][256] =============
__device__ __forceinline__ float silu_f(float x) { return x / (1.0f + expf(-x)); }

__global__ __launch_bounds__(256) void k_gemm_silu(float* __restrict__ h,
                                                   const float* __restrict__ W,
                                                   const float* __restrict__ bias,
                                                   int n1) {
    __shared__ float As[32 * DD];  // 32 KB
    const int t = threadIdx.x;
    const int row0 = blockIdx.x * 32;

    const float4* hv = (const float4*)h;
    float4* As4 = (float4*)As;
#pragma unroll
    for (int i = 0; i < 8; ++i) {
        int idx = t + i * 256;
        int r = idx >> 6, c = idx & 63;
        int gr = row0 + r;
        float4 v = make_float4(0.f, 0.f, 0.f, 0.f);
        if (gr < n1) v = hv[(size_t)gr * 64 + c];
        As4[idx] = v;
    }
    __syncthreads();

    const int rg = t >> 6;
    const int cg = t & 63;
    const float4* Wv = (const float4*)W;

    float4 acc[8];
#pragma unroll
    for (int r = 0; r < 8; ++r) acc[r] = make_float4(0.f, 0.f, 0.f, 0.f);

    for (int k = 0; k < DD; k += 4) {
        float4 a[8];
#pragma unroll
        for (int r = 0; r < 8; ++r)
            a[r] = *(const float4*)&As[(rg * 8 + r) * DD + k];
#pragma unroll
        for (int kk = 0; kk < 4; ++kk) {
            float4 w = Wv[(size_t)(k + kk) * 64 + cg];
#pragma unroll
            for (int r = 0; r < 8; ++r) {
                float av = (kk == 0) ? a[r].x : (kk == 1) ? a[r].y
                         : (kk == 2) ? a[r].z : a[r].w;
                acc[r].x += av * w.x;
                acc[r].y += av * w.y;
                acc[r].z += av * w.z;
                acc[r].w += av * w.w;
            }
        }
    }

    float4 bb = ((const float4*)bias)[cg];
    float4* ho = (float4*)h;
#pragma unroll
    for (int r = 0; r < 8; ++r) {
        int gr = row0 + rg * 8 + r;
        if (gr >= n1) continue;
        float4 x = acc[r];
        x.x = silu_f(x.x + bb.x);
        x.y = silu_f(x.y + bb.y);
        x.z = silu_f(x.z + bb.z);
        x.w = silu_f(x.w + bb.w);
        ho[(size_t)gr * 64 + cg] = x;
    }
}

// ================= launcher ================================================
static inline size_t al16(size_t x) { return (x + 15) & ~(size_t)15; }

extern "C" void kernel_launch(void* const* d_in, const int* in_sizes, int n_in,
                              void* d_out, int out_size, void* d_ws, size_t ws_size,
                              hipStream_t stream) {
    const float* feat = (const float*)d_in[0];
    const int* c2a = (const int*)d_in[1];
    const int* c2b = (const int*)d_in[2];
    const int* c3a = (const int*)d_in[3];
    const int* c3b = (const int*)d_in[4];
    const int* c4a = (const int*)d_in[5];
    const int* c4b = (const int*)d_in[6];
    const float* W = (const float*)d_in[7];
    const float* bias = (const float*)d_in[8];

    const int N1 = in_sizes[0] / DD;
    const int N2 = in_sizes[1];
    const int N3 = in_sizes[3];
    const int N4 = in_sizes[5];
    float* out = (float*)d_out;
    char* ws = (char*)d_ws;

    dim3 blk(256);
    auto rows_grid = [](int n) { return dim3((unsigned)((n + 3) / 4)); };
    auto thr_grid = [](int n) { return dim3((unsigned)((n + 255) / 256)); };

    int maxN = N1 > N2 ? N1 : N2;
    if (N3 > maxN) maxN = N3;

    // ---- scratch layout ----
    size_t cnt_b   = al16((size_t)maxN * 4);
    size_t bsum_b  = al16(4096);
    size_t offs4_b = al16((size_t)(N3 + 1) * 4);
    size_t entp_b  = al16((size_t)2 * N4 * 8);       // int2 per incidence
    size_t offs3_b = al16((size_t)(N2 + 1) * 4);
    size_t ent3_b  = al16((size_t)2 * N3 * 4);
    size_t offs2_b = al16((size_t)(N1 + 1) * 4);
    size_t ent2_b  = al16((size_t)2 * N2 * 4);
    size_t offsF_b = al16((size_t)(N1 + 1) * 4);
    size_t entF_b  = al16((size_t)4 * N3 * 4);       // 4*N3 flat entries
    size_t fixed_b = cnt_b + bsum_b + offs4_b + entp_b + offs3_b + ent3_b +
                     offs2_b + ent2_b + offsF_b + entF_b;
    size_t h2_b = (size_t)N2 * DD * sizeof(float);

    char* p = ws;
    int* cnt   = (int*)p; p += cnt_b;
    int* bsum  = (int*)p; p += bsum_b;
    int* offs4 = (int*)p; p += offs4_b;
    int2* entp = (int2*)p; p += entp_b;
    int* offs3 = (int*)p; p += offs3_b;
    int* ent3  = (int*)p; p += ent3_b;
    int* offs2 = (int*)p; p += offs2_b;
    int* ent2  = (int*)p; p += ent2_b;
    int* offsF = (int*)p; p += offsF_b;
    int* entF  = (int*)p; p += entF_b;
    float* h2  = (float*)p; p += h2_b;
    float* h3chunk = (float*)p;

    size_t free_b = (ws_size > fixed_b + h2_b) ? ws_size - fixed_b - h2_b : 0;
    int chunk_rows = (int)(free_b / ((size_t)DD * sizeof(float)));
    if (chunk_rows > N3) chunk_rows = N3;
    if (chunk_rows < 1) chunk_rows = 1;   // (ws known >= 212 MB; never hit)
    int C = (N3 + chunk_rows - 1) / chunk_rows;
    chunk_rows = (N3 + C - 1) / C;        // balance chunks

    auto scan_offs = [&](int* cn, int nnode, int* offs) {
        int nb = (nnode + SCAN_ELEMS - 1) / SCAN_ELEMS;
        k_block_sums<<<dim3((unsigned)nb), dim3(SCAN_BLK), 0, stream>>>(cn, nnode, bsum);
        k_scan_bsums<<<dim3(1), dim3(64), 0, stream>>>(bsum, nb, offs + nnode);
        k_scan_final<<<dim3((unsigned)nb), dim3(SCAN_BLK), 0, stream>>>(cn, nnode, bsum, offs);
    };

    // ---- CSR4 with pair payload ----
    hipMemsetAsync(cnt, 0, (size_t)N3 * 4, stream);
    k_count_pairs<<<thr_grid(N4), blk, 0, stream>>>(c4a, c4b, N4, cnt);
    scan_offs(cnt, N3, offs4);
    hipMemcpyAsync(cnt, offs4, (size_t)N3 * 4, hipMemcpyDeviceToDevice, stream);
    k_fill_pairs4<<<thr_grid(N4), blk, 0, stream>>>(c4a, c4b, c3a, c3b, N4, cnt, entp);

    // ---- CSR3 (edge ids) ----
    hipMemsetAsync(cnt, 0, (size_t)N2 * 4, stream);
    k_count_pairs<<<thr_grid(N3), blk, 0, stream>>>(c3a, c3b, N3, cnt);
    scan_offs(cnt, N2, offs3);
    hipMemcpyAsync(cnt, offs3, (size_t)N2 * 4, hipMemcpyDeviceToDevice, stream);
    k_fill_edges<<<thr_grid(N3), blk, 0, stream>>>(c3a, c3b, N3, cnt, ent3);

    // ---- CSR2 (edge ids) ----
    hipMemsetAsync(cnt, 0, (size_t)N1 * 4, stream);
    k_count_pairs<<<thr_grid(N2), blk, 0, stream>>>(c2a, c2b, N2, cnt);
    scan_offs(cnt, N1, offs2);
    hipMemcpyAsync(cnt, offs2, (size_t)N1 * 4, hipMemcpyDeviceToDevice, stream);
    k_fill_edges<<<thr_grid(N2), blk, 0, stream>>>(c2a, c2b, N2, cnt, ent2);

    // ---- flat i -> {level-3 edge} list ----
    k_flat_cnt<<<thr_grid(N1), blk, 0, stream>>>(offs2, ent2, offs3, N1, cnt);
    scan_offs(cnt, N1, offsF);
    k_flat_fill<<<thr_grid(N1), blk, 0, stream>>>(offs2, ent2, offs3, ent3, offsF, N1, entF);

    // ---- dense sweeps ----
    k_h2<<<rows_grid(N2), blk, 0, stream>>>(feat, c2a, c2b, h2, N2);
    k_out_init<<<rows_grid(N1), blk, 0, stream>>>(feat, h2, offs2, ent2, out, N1);

    for (int lo = 0; lo < N3; lo += chunk_rows) {
        int hi = lo + chunk_rows;
        if (hi > N3) hi = N3;
        k_h3tot_h2<<<rows_grid(hi - lo), blk, 0, stream>>>(h2, c3a, c3b, offs4, entp,
                                                           h3chunk, lo, hi);
        k_h1_flat<<<rows_grid(N1), blk, 0, stream>>>(offsF, entF, h3chunk, out, N1, lo, hi);
    }

    // out = silu(out @ W + b), in-place
    k_gemm_silu<<<dim3((unsigned)((N1 + 31) / 32)), blk, 0, stream>>>(out, W, bias, N1);
}

// Round 6
// 852.753 us; speedup vs baseline: 6.4715x; 1.0050x over previous
//
#include <hip/hip_runtime.h>
#include <cstdint>
#include <cstddef>

#define DD 256    // full feature dim
#define DH 128    // half feature dim (dim-split pipeline)
#define SCAN_BLK 256
#define SCAN_ELEMS 2048  // 8 per thread

// ---------- helpers --------------------------------------------------------
__device__ __forceinline__ float2 mul2(float2 a, float2 b) {
    return make_float2(a.x * b.x, a.y * b.y);
}
__device__ __forceinline__ float2 add2(float2 a, float2 b) {
    return make_float2(a.x + b.x, a.y + b.y);
}
// load 2 floats of a 128-wide row (lane covers elems 2*lane, 2*lane+1)
__device__ __forceinline__ float2 ldh(const float* __restrict__ base, int row, int lane) {
    return ((const float2*)(base + (size_t)row * DH))[lane];
}
// load 2 floats from a 256-wide row at column offset doff
__device__ __forceinline__ float2 ldf(const float* __restrict__ base, int row, int doff, int lane) {
    return ((const float2*)(base + (size_t)row * DD + doff))[lane];
}

// ================= CSR build (int atomics only) ============================
__global__ void k_count_pairs(const int* __restrict__ ea, const int* __restrict__ eb,
                              int ne, int* __restrict__ cnt) {
    int e = blockIdx.x * blockDim.x + threadIdx.x;
    if (e >= ne) return;
    atomicAdd(&cnt[ea[e]], 1);
    atomicAdd(&cnt[eb[e]], 1);
}

__global__ void k_fill_edges(const int* __restrict__ ea, const int* __restrict__ eb,
                             int ne, int* __restrict__ cursor, int* __restrict__ ent) {
    int e = blockIdx.x * blockDim.x + threadIdx.x;
    if (e >= ne) return;
    int a = ea[e], b = eb[e];
    int pa = atomicAdd(&cursor[a], 1);
    int pb = atomicAdd(&cursor[b], 1);
    ent[pa] = e;
    ent[pb] = e;
}

// level-4 incidence: store the OTHER endpoint's (c3a,c3b) pair directly
__global__ void k_fill_pairs4(const int* __restrict__ c4a, const int* __restrict__ c4b,
                              const int* __restrict__ c3a, const int* __restrict__ c3b,
                              int ne, int* __restrict__ cursor, int2* __restrict__ entp) {
    int e = blockIdx.x * blockDim.x + threadIdx.x;
    if (e >= ne) return;
    int a = c4a[e], b = c4b[e];
    int2 prA = make_int2(c3a[b], c3b[b]);
    int2 prB = make_int2(c3a[a], c3b[a]);
    int pa = atomicAdd(&cursor[a], 1);
    int pb = atomicAdd(&cursor[b], 1);
    entp[pa] = prA;
    entp[pb] = prB;
}

__global__ void k_block_sums(const int* __restrict__ cnt, int n, int* __restrict__ bsum) {
    __shared__ int sdata[SCAN_BLK];
    int base = blockIdx.x * SCAN_ELEMS;
    int s = 0;
#pragma unroll
    for (int k = 0; k < 8; ++k) {
        int idx = base + threadIdx.x + k * SCAN_BLK;
        if (idx < n) s += cnt[idx];
    }
    sdata[threadIdx.x] = s;
    __syncthreads();
    for (int off = SCAN_BLK / 2; off > 0; off >>= 1) {
        if (threadIdx.x < off) sdata[threadIdx.x] += sdata[threadIdx.x + off];
        __syncthreads();
    }
    if (threadIdx.x == 0) bsum[blockIdx.x] = sdata[0];
}

__global__ void k_scan_bsums(int* __restrict__ bsum, int nb, int* __restrict__ total_out) {
    if (threadIdx.x == 0 && blockIdx.x == 0) {
        int acc = 0;
        for (int b = 0; b < nb; ++b) { int v = bsum[b]; bsum[b] = acc; acc += v; }
        *total_out = acc;
    }
}

__global__ void k_scan_final(const int* __restrict__ cnt, int n,
                             const int* __restrict__ bsum, int* __restrict__ offs) {
    __shared__ int sdata[SCAN_BLK];
    int base = blockIdx.x * SCAN_ELEMS;
    int t0 = base + threadIdx.x * 8;
    int loc[8];
    int s = 0;
#pragma unroll
    for (int k = 0; k < 8; ++k) {
        int idx = t0 + k;
        int v = (idx < n) ? cnt[idx] : 0;
        loc[k] = s;
        s += v;
    }
    sdata[threadIdx.x] = s;
    __syncthreads();
    int run = s;
    for (int off = 1; off < SCAN_BLK; off <<= 1) {
        int add = (threadIdx.x >= (unsigned)off) ? sdata[threadIdx.x - off] : 0;
        __syncthreads();
        run += add;
        sdata[threadIdx.x] = run;
        __syncthreads();
    }
    int texcl = run - s + bsum[blockIdx.x];
#pragma unroll
    for (int k = 0; k < 8; ++k) {
        int idx = t0 + k;
        if (idx < n) offs[idx] = texcl + loc[k];
    }
}

// ========== flat i -> {level-3 edge} list (composition of CSR2 and CSR3) ===
__global__ void k_flat_cnt(const int* __restrict__ offs2, const int* __restrict__ ent2,
                           const int* __restrict__ offs3, int n1, int* __restrict__ cntF) {
    int i = blockIdx.x * blockDim.x + threadIdx.x;
    if (i >= n1) return;
    int c = 0;
    int e0 = offs2[i], e1 = offs2[i + 1];
    for (int e = e0; e < e1; ++e) {
        int q = ent2[e];
        c += offs3[q + 1] - offs3[q];
    }
    cntF[i] = c;
}

__global__ void k_flat_fill(const int* __restrict__ offs2, const int* __restrict__ ent2,
                            const int* __restrict__ offs3, const int* __restrict__ ent3,
                            const int* __restrict__ offsF, int n1, int* __restrict__ entF) {
    int i = blockIdx.x * blockDim.x + threadIdx.x;
    if (i >= n1) return;
    int pos = offsF[i];
    int e0 = offs2[i], e1 = offs2[i + 1];
    for (int e = e0; e < e1; ++e) {
        int q = ent2[e];
        int f0 = offs3[q], f1 = offs3[q + 1];
        for (int f = f0; f < f1; ++f) entF[pos++] = ent3[f];
    }
}

// ================= dim-split dense sweeps ==================================
// h2h[q][0..127] = feat[c2a[q]][doff..] * feat[c2b[q]][doff..]
__global__ void k_h2_half(const float* __restrict__ feat, const int* __restrict__ c2a,
                          const int* __restrict__ c2b, float* __restrict__ h2h,
                          int n2, int doff) {
    int q = blockIdx.x * 4 + (threadIdx.x >> 6);
    int lane = threadIdx.x & 63;
    if (q >= n2) return;
    float2 v = mul2(ldf(feat, c2a[q], doff, lane), ldf(feat, c2b[q], doff, lane));
    ((float2*)(h2h + (size_t)q * DH))[lane] = v;
}

// h3th[j-lo] = own * (1 + sum_e h2h[p.x]*h2h[p.y]); own = h2h[c3a[j]]*h2h[c3b[j]]
__global__ void k_h3tot_half(const float* __restrict__ h2h,
                             const int* __restrict__ c3a, const int* __restrict__ c3b,
                             const int* __restrict__ offs4, const int2* __restrict__ entp,
                             float* __restrict__ h3th, int lo, int hi) {
    int j = lo + blockIdx.x * 4 + (threadIdx.x >> 6);
    int lane = threadIdx.x & 63;
    if (j >= hi) return;
    float2 own = mul2(ldh(h2h, c3a[j], lane), ldh(h2h, c3b[j], lane));
    float2 s = make_float2(0.f, 0.f);
    int e0 = offs4[j], e1 = offs4[j + 1];
    int e = e0;
    for (; e + 1 < e1; e += 2) {
        int2 p0 = entp[e], p1 = entp[e + 1];
        float2 a0 = ldh(h2h, p0.x, lane), b0 = ldh(h2h, p0.y, lane);
        float2 a1 = ldh(h2h, p1.x, lane), b1 = ldh(h2h, p1.y, lane);
        s = add2(s, add2(mul2(a0, b0), mul2(a1, b1)));
    }
    if (e < e1) {
        int2 p = entp[e];
        s = add2(s, mul2(ldh(h2h, p.x, lane), ldh(h2h, p.y, lane)));
    }
    float2 r = mul2(own, make_float2(1.f + s.x, 1.f + s.y));
    ((float2*)(h3th + (size_t)(j - lo) * DH))[lane] = r;
}

// out[i][doff..] = (init: feat[i]+sum h2h[q] | else: out[i]) + sum_{j in [lo,hi)} h3th[j-lo]
__global__ void k_h1_half(const float* __restrict__ feat, const float* __restrict__ h2h,
                          const int* __restrict__ offs2, const int* __restrict__ ent2,
                          const int* __restrict__ offsF, const int* __restrict__ entF,
                          const float* __restrict__ h3th, float* __restrict__ out,
                          int n1, int lo, int hi, int do_init, int doff) {
    int i = blockIdx.x * 4 + (threadIdx.x >> 6);
    int lane = threadIdx.x & 63;
    if (i >= n1) return;
    float2 h;
    if (do_init) {
        h = ldf(feat, i, doff, lane);
        int e0 = offs2[i], e1 = offs2[i + 1];
        int e = e0;
        for (; e + 1 < e1; e += 2) {
            int q0 = ent2[e], q1 = ent2[e + 1];
            h = add2(h, add2(ldh(h2h, q0, lane), ldh(h2h, q1, lane)));
        }
        if (e < e1) h = add2(h, ldh(h2h, ent2[e], lane));
    } else {
        h = ldf(out, i, doff, lane);
    }
    int f0 = offsF[i], f1 = offsF[i + 1];
    int f = f0;
    for (; f + 1 < f1; f += 2) {
        int j0 = entF[f], j1 = entF[f + 1];
        bool in0 = (j0 >= lo) && (j0 < hi);
        bool in1 = (j1 >= lo) && (j1 < hi);
        if (in0 && in1) {
            h = add2(h, add2(ldh(h3th, j0 - lo, lane), ldh(h3th, j1 - lo, lane)));
        } else if (in0) {
            h = add2(h, ldh(h3th, j0 - lo, lane));
        } else if (in1) {
            h = add2(h, ldh(h3th, j1 - lo, lane));
        }
    }
    if (f < f1) {
        int j0 = entF[f];
        if (j0 >= lo && j0 < hi) h = add2(h, ldh(h3th, j0 - lo, lane));
    }
    ((float2*)(out + (size_t)i * DD + doff))[lane] = h;
}

// ================= GEMM + bias + SiLU, in-place on h [n1][256] =============
__device__ __forceinline__ float silu_f(float x) { return x / (1.0f + expf(-x)); }

__global__ __launch_bounds__(256) void k_gemm_silu(float* __restrict__ h,
                                                   const float* __restrict__ W,
                                                   const float* __restrict__ bias,
                                                   int n1) {
    __shared__ float As[32 * DD];  // 32 KB
    const int t = threadIdx.x;
    const int row0 = blockIdx.x * 32;

    const float4* hv = (const float4*)h;
    float4* As4 = (float4*)As;
#pragma unroll
    for (int i = 0; i < 8; ++i) {
        int idx = t + i * 256;
        int r = idx >> 6, c = idx & 63;
        int gr = row0 + r;
        float4 v = make_float4(0.f, 0.f, 0.f, 0.f);
        if (gr < n1) v = hv[(size_t)gr * 64 + c];
        As4[idx] = v;
    }
    __syncthreads();

    const int rg = t >> 6;
    const int cg = t & 63;
    const float4* Wv = (const float4*)W;

    float4 acc[8];
#pragma unroll
    for (int r = 0; r < 8; ++r) acc[r] = make_float4(0.f, 0.f, 0.f, 0.f);

    for (int k = 0; k < DD; k += 4) {
        float4 a[8];
#pragma unroll
        for (int r = 0; r < 8; ++r)
            a[r] = *(const float4*)&As[(rg * 8 + r) * DD + k];
#pragma unroll
        for (int kk = 0; kk < 4; ++kk) {
            float4 w = Wv[(size_t)(k + kk) * 64 + cg];
#pragma unroll
            for (int r = 0; r < 8; ++r) {
                float av = (kk == 0) ? a[r].x : (kk == 1) ? a[r].y
                         : (kk == 2) ? a[r].z : a[r].w;
                acc[r].x += av * w.x;
                acc[r].y += av * w.y;
                acc[r].z += av * w.z;
                acc[r].w += av * w.w;
            }
        }
    }

    float4 bb = ((const float4*)bias)[cg];
    float4* ho = (float4*)h;
#pragma unroll
    for (int r = 0; r < 8; ++r) {
        int gr = row0 + rg * 8 + r;
        if (gr >= n1) continue;
        float4 x = acc[r];
        x.x = silu_f(x.x + bb.x);
        x.y = silu_f(x.y + bb.y);
        x.z = silu_f(x.z + bb.z);
        x.w = silu_f(x.w + bb.w);
        ho[(size_t)gr * 64 + cg] = x;
    }
}

// ================= launcher ================================================
static inline size_t al16(size_t x) { return (x + 15) & ~(size_t)15; }

extern "C" void kernel_launch(void* const* d_in, const int* in_sizes, int n_in,
                              void* d_out, int out_size, void* d_ws, size_t ws_size,
                              hipStream_t stream) {
    const float* feat = (const float*)d_in[0];
    const int* c2a = (const int*)d_in[1];
    const int* c2b = (const int*)d_in[2];
    const int* c3a = (const int*)d_in[3];
    const int* c3b = (const int*)d_in[4];
    const int* c4a = (const int*)d_in[5];
    const int* c4b = (const int*)d_in[6];
    const float* W = (const float*)d_in[7];
    const float* bias = (const float*)d_in[8];

    const int N1 = in_sizes[0] / DD;
    const int N2 = in_sizes[1];
    const int N3 = in_sizes[3];
    const int N4 = in_sizes[5];
    float* out = (float*)d_out;
    char* ws = (char*)d_ws;

    dim3 blk(256);
    auto rows_grid = [](int n) { return dim3((unsigned)((n + 3) / 4)); };
    auto thr_grid = [](int n) { return dim3((unsigned)((n + 255) / 256)); };

    int maxN = N1 > N2 ? N1 : N2;
    if (N3 > maxN) maxN = N3;

    // ---- scratch layout ----
    size_t cnt_b   = al16((size_t)maxN * 4);
    size_t bsum_b  = al16(4096);
    size_t offs4_b = al16((size_t)(N3 + 1) * 4);
    size_t entp_b  = al16((size_t)2 * N4 * 8);       // int2 per incidence
    size_t offs3_b = al16((size_t)(N2 + 1) * 4);
    size_t ent3_b  = al16((size_t)2 * N3 * 4);
    size_t offs2_b = al16((size_t)(N1 + 1) * 4);
    size_t ent2_b  = al16((size_t)2 * N2 * 4);
    size_t offsF_b = al16((size_t)(N1 + 1) * 4);
    size_t entF_b  = al16((size_t)4 * N3 * 4);       // exactly 4*N3 entries
    size_t fixed_b = cnt_b + bsum_b + offs4_b + entp_b + offs3_b + ent3_b +
                     offs2_b + ent2_b + offsF_b + entF_b;
    size_t h2h_b = (size_t)N2 * DH * sizeof(float);  // 51.2 MB

    char* p = ws;
    int* cnt   = (int*)p; p += cnt_b;
    int* bsum  = (int*)p; p += bsum_b;
    int* offs4 = (int*)p; p += offs4_b;
    int2* entp = (int2*)p; p += entp_b;
    int* offs3 = (int*)p; p += offs3_b;
    int* ent3  = (int*)p; p += ent3_b;
    int* offs2 = (int*)p; p += offs2_b;
    int* ent2  = (int*)p; p += ent2_b;
    int* offsF = (int*)p; p += offsF_b;
    int* entF  = (int*)p; p += entF_b;
    float* h2h = (float*)p; p += h2h_b;
    float* h3th = (float*)p;                          // chunk buffer (half rows)

    size_t free_b = (ws_size > fixed_b + h2h_b) ? ws_size - fixed_b - h2h_b : 0;
    int chunk_rows = (int)(free_b / ((size_t)DH * sizeof(float)));
    if (chunk_rows > N3) chunk_rows = N3;
    if (chunk_rows < 1) chunk_rows = 1;
    int C = (N3 + chunk_rows - 1) / chunk_rows;
    chunk_rows = (N3 + C - 1) / C;   // balance (C==1 expected: 102.4 MB fits)

    auto scan_offs = [&](int* cn, int nnode, int* offs) {
        int nb = (nnode + SCAN_ELEMS - 1) / SCAN_ELEMS;
        k_block_sums<<<dim3((unsigned)nb), dim3(SCAN_BLK), 0, stream>>>(cn, nnode, bsum);
        k_scan_bsums<<<dim3(1), dim3(64), 0, stream>>>(bsum, nb, offs + nnode);
        k_scan_final<<<dim3((unsigned)nb), dim3(SCAN_BLK), 0, stream>>>(cn, nnode, bsum, offs);
    };

    // ---- CSR4 with pair payload ----
    hipMemsetAsync(cnt, 0, (size_t)N3 * 4, stream);
    k_count_pairs<<<thr_grid(N4), blk, 0, stream>>>(c4a, c4b, N4, cnt);
    scan_offs(cnt, N3, offs4);
    hipMemcpyAsync(cnt, offs4, (size_t)N3 * 4, hipMemcpyDeviceToDevice, stream);
    k_fill_pairs4<<<thr_grid(N4), blk, 0, stream>>>(c4a, c4b, c3a, c3b, N4, cnt, entp);

    // ---- CSR3 (edge ids) ----
    hipMemsetAsync(cnt, 0, (size_t)N2 * 4, stream);
    k_count_pairs<<<thr_grid(N3), blk, 0, stream>>>(c3a, c3b, N3, cnt);
    scan_offs(cnt, N2, offs3);
    hipMemcpyAsync(cnt, offs3, (size_t)N2 * 4, hipMemcpyDeviceToDevice, stream);
    k_fill_edges<<<thr_grid(N3), blk, 0, stream>>>(c3a, c3b, N3, cnt, ent3);

    // ---- CSR2 (edge ids) ----
    hipMemsetAsync(cnt, 0, (size_t)N1 * 4, stream);
    k_count_pairs<<<thr_grid(N2), blk, 0, stream>>>(c2a, c2b, N2, cnt);
    scan_offs(cnt, N1, offs2);
    hipMemcpyAsync(cnt, offs2, (size_t)N1 * 4, hipMemcpyDeviceToDevice, stream);
    k_fill_edges<<<thr_grid(N2), blk, 0, stream>>>(c2a, c2b, N2, cnt, ent2);

    // ---- flat i -> {level-3 edge} list ----
    k_flat_cnt<<<thr_grid(N1), blk, 0, stream>>>(offs2, ent2, offs3, N1, cnt);
    scan_offs(cnt, N1, offsF);
    k_flat_fill<<<thr_grid(N1), blk, 0, stream>>>(offs2, ent2, offs3, ent3, offsF, N1, entF);

    // ---- dim-split dense sweeps: half d in {0,128} ----
    for (int doff = 0; doff < DD; doff += DH) {
        k_h2_half<<<rows_grid(N2), blk, 0, stream>>>(feat, c2a, c2b, h2h, N2, doff);
        int do_init = 1;
        for (int lo = 0; lo < N3; lo += chunk_rows) {
            int hi = lo + chunk_rows;
            if (hi > N3) hi = N3;
            k_h3tot_half<<<rows_grid(hi - lo), blk, 0, stream>>>(h2h, c3a, c3b,
                                                                 offs4, entp,
                                                                 h3th, lo, hi);
            k_h1_half<<<rows_grid(N1), blk, 0, stream>>>(feat, h2h, offs2, ent2,
                                                         offsF, entF, h3th, out,
                                                         N1, lo, hi, do_init, doff);
            do_init = 0;
        }
    }

    // out = silu(out @ W + b), in-place
    k_gemm_silu<<<dim3((unsigned)((N1 + 31) / 32)), blk, 0, stream>>>(out, W, bias, N1);
}

// Round 7
// 776.700 us; speedup vs baseline: 7.1052x; 1.0979x over previous
//
#include <hip/hip_runtime.h>
#include <cstdint>
#include <cstddef>

#define DD 256    // full feature dim
#define DH 128    // half feature dim (dim-split pipeline)
#define SCAN_BLK 256
#define SCAN_ELEMS 2048  // 8 per thread

// ---------- helpers --------------------------------------------------------
__device__ __forceinline__ float2 mul2(float2 a, float2 b) {
    return make_float2(a.x * b.x, a.y * b.y);
}
__device__ __forceinline__ float2 add2(float2 a, float2 b) {
    return make_float2(a.x + b.x, a.y + b.y);
}
// load 2 floats of a 128-wide row (lane covers elems 2*lane, 2*lane+1)
__device__ __forceinline__ float2 ldh(const float* __restrict__ base, int row, int lane) {
    return ((const float2*)(base + (size_t)row * DH))[lane];
}
// load 2 floats from a 256-wide row at column offset doff
__device__ __forceinline__ float2 ldf(const float* __restrict__ base, int row, int doff, int lane) {
    return ((const float2*)(base + (size_t)row * DD + doff))[lane];
}

// ================= CSR build (int atomics only) ============================
__global__ void k_count_pairs(const int* __restrict__ ea, const int* __restrict__ eb,
                              int ne, int* __restrict__ cnt) {
    int e = blockIdx.x * blockDim.x + threadIdx.x;
    if (e >= ne) return;
    atomicAdd(&cnt[ea[e]], 1);
    atomicAdd(&cnt[eb[e]], 1);
}

__global__ void k_fill_edges(const int* __restrict__ ea, const int* __restrict__ eb,
                             int ne, int* __restrict__ cursor, int* __restrict__ ent) {
    int e = blockIdx.x * blockDim.x + threadIdx.x;
    if (e >= ne) return;
    int a = ea[e], b = eb[e];
    int pa = atomicAdd(&cursor[a], 1);
    int pb = atomicAdd(&cursor[b], 1);
    ent[pa] = e;
    ent[pb] = e;
}

// level-4 incidence: store the OTHER endpoint's (c3a,c3b) pair directly
__global__ void k_fill_pairs4(const int* __restrict__ c4a, const int* __restrict__ c4b,
                              const int* __restrict__ c3a, const int* __restrict__ c3b,
                              int ne, int* __restrict__ cursor, int2* __restrict__ entp) {
    int e = blockIdx.x * blockDim.x + threadIdx.x;
    if (e >= ne) return;
    int a = c4a[e], b = c4b[e];
    int2 prA = make_int2(c3a[b], c3b[b]);
    int2 prB = make_int2(c3a[a], c3b[a]);
    int pa = atomicAdd(&cursor[a], 1);
    int pb = atomicAdd(&cursor[b], 1);
    entp[pa] = prA;
    entp[pb] = prB;
}

__global__ void k_block_sums(const int* __restrict__ cnt, int n, int* __restrict__ bsum) {
    __shared__ int sdata[SCAN_BLK];
    int base = blockIdx.x * SCAN_ELEMS;
    int s = 0;
#pragma unroll
    for (int k = 0; k < 8; ++k) {
        int idx = base + threadIdx.x + k * SCAN_BLK;
        if (idx < n) s += cnt[idx];
    }
    sdata[threadIdx.x] = s;
    __syncthreads();
    for (int off = SCAN_BLK / 2; off > 0; off >>= 1) {
        if (threadIdx.x < off) sdata[threadIdx.x] += sdata[threadIdx.x + off];
        __syncthreads();
    }
    if (threadIdx.x == 0) bsum[blockIdx.x] = sdata[0];
}

__global__ void k_scan_bsums(int* __restrict__ bsum, int nb, int* __restrict__ total_out) {
    if (threadIdx.x == 0 && blockIdx.x == 0) {
        int acc = 0;
        for (int b = 0; b < nb; ++b) { int v = bsum[b]; bsum[b] = acc; acc += v; }
        *total_out = acc;
    }
}

__global__ void k_scan_final(const int* __restrict__ cnt, int n,
                             const int* __restrict__ bsum, int* __restrict__ offs) {
    __shared__ int sdata[SCAN_BLK];
    int base = blockIdx.x * SCAN_ELEMS;
    int t0 = base + threadIdx.x * 8;
    int loc[8];
    int s = 0;
#pragma unroll
    for (int k = 0; k < 8; ++k) {
        int idx = t0 + k;
        int v = (idx < n) ? cnt[idx] : 0;
        loc[k] = s;
        s += v;
    }
    sdata[threadIdx.x] = s;
    __syncthreads();
    int run = s;
    for (int off = 1; off < SCAN_BLK; off <<= 1) {
        int add = (threadIdx.x >= (unsigned)off) ? sdata[threadIdx.x - off] : 0;
        __syncthreads();
        run += add;
        sdata[threadIdx.x] = run;
        __syncthreads();
    }
    int texcl = run - s + bsum[blockIdx.x];
#pragma unroll
    for (int k = 0; k < 8; ++k) {
        int idx = t0 + k;
        if (idx < n) offs[idx] = texcl + loc[k];
    }
}

// ================= dim-split dense sweeps ==================================
// h2h[q][0..127] = feat[c2a[q]][doff..] * feat[c2b[q]][doff..]
__global__ void k_h2_half(const float* __restrict__ feat, const int* __restrict__ c2a,
                          const int* __restrict__ c2b, float* __restrict__ h2h,
                          int n2, int doff) {
    int q = blockIdx.x * 4 + (threadIdx.x >> 6);
    int lane = threadIdx.x & 63;
    if (q >= n2) return;
    float2 v = mul2(ldf(feat, c2a[q], doff, lane), ldf(feat, c2b[q], doff, lane));
    ((float2*)(h2h + (size_t)q * DH))[lane] = v;
}

// h3th[j-lo] = own * (1 + sum_e h2h[p.x]*h2h[p.y]); own = h2h[c3a[j]]*h2h[c3b[j]]
__global__ void k_h3tot_half(const float* __restrict__ h2h,
                             const int* __restrict__ c3a, const int* __restrict__ c3b,
                             const int* __restrict__ offs4, const int2* __restrict__ entp,
                             float* __restrict__ h3th, int lo, int hi) {
    int j = lo + blockIdx.x * 4 + (threadIdx.x >> 6);
    int lane = threadIdx.x & 63;
    if (j >= hi) return;
    float2 own = mul2(ldh(h2h, c3a[j], lane), ldh(h2h, c3b[j], lane));
    float2 s = make_float2(0.f, 0.f);
    int e0 = offs4[j], e1 = offs4[j + 1];
    int e = e0;
    for (; e + 1 < e1; e += 2) {
        int2 p0 = entp[e], p1 = entp[e + 1];
        float2 a0 = ldh(h2h, p0.x, lane), b0 = ldh(h2h, p0.y, lane);
        float2 a1 = ldh(h2h, p1.x, lane), b1 = ldh(h2h, p1.y, lane);
        s = add2(s, add2(mul2(a0, b0), mul2(a1, b1)));
    }
    if (e < e1) {
        int2 p = entp[e];
        s = add2(s, mul2(ldh(h2h, p.x, lane), ldh(h2h, p.y, lane)));
    }
    float2 r = mul2(own, make_float2(1.f + s.x, 1.f + s.y));
    ((float2*)(h3th + (size_t)(j - lo) * DH))[lane] = r;
}

// m2 mailbox: dst[q] = (first ? h2h[q] : dst[q]) + sum_{j in CSR3[q], j in [lo,hi)} h3th[j-lo]
// primary path: dst == h2h (in place, race-free: wave touches only its own row)
__global__ void k_m2_half(const float* __restrict__ h2h,
                          const int* __restrict__ offs3, const int* __restrict__ ent3,
                          const float* __restrict__ h3th, float* __restrict__ dst,
                          int n2, int lo, int hi, int first) {
    int q = blockIdx.x * 4 + (threadIdx.x >> 6);
    int lane = threadIdx.x & 63;
    if (q >= n2) return;
    float2 h = first ? ldh(h2h, q, lane) : ldh(dst, q, lane);
    int f0 = offs3[q], f1 = offs3[q + 1];
    int f = f0;
    for (; f + 1 < f1; f += 2) {
        int j0 = ent3[f], j1 = ent3[f + 1];
        bool in0 = (j0 >= lo) && (j0 < hi);
        bool in1 = (j1 >= lo) && (j1 < hi);
        if (in0 && in1) {
            h = add2(h, add2(ldh(h3th, j0 - lo, lane), ldh(h3th, j1 - lo, lane)));
        } else if (in0) {
            h = add2(h, ldh(h3th, j0 - lo, lane));
        } else if (in1) {
            h = add2(h, ldh(h3th, j1 - lo, lane));
        }
    }
    if (f < f1) {
        int j0 = ent3[f];
        if (j0 >= lo && j0 < hi) h = add2(h, ldh(h3th, j0 - lo, lane));
    }
    ((float2*)(dst + (size_t)q * DH))[lane] = h;
}

// out[i][doff..] = feat[i][doff..] + sum_{q in CSR2[i]} m2[q]
__global__ void k_h1_half(const float* __restrict__ feat, const float* __restrict__ m2,
                          const int* __restrict__ offs2, const int* __restrict__ ent2,
                          float* __restrict__ out, int n1, int doff) {
    int i = blockIdx.x * 4 + (threadIdx.x >> 6);
    int lane = threadIdx.x & 63;
    if (i >= n1) return;
    float2 h = ldf(feat, i, doff, lane);
    int e0 = offs2[i], e1 = offs2[i + 1];
    int e = e0;
    for (; e + 1 < e1; e += 2) {
        int q0 = ent2[e], q1 = ent2[e + 1];
        h = add2(h, add2(ldh(m2, q0, lane), ldh(m2, q1, lane)));
    }
    if (e < e1) h = add2(h, ldh(m2, ent2[e], lane));
    ((float2*)(out + (size_t)i * DD + doff))[lane] = h;
}

// ================= GEMM + bias + SiLU, in-place on h [n1][256] =============
__device__ __forceinline__ float silu_f(float x) { return x / (1.0f + expf(-x)); }

__global__ __launch_bounds__(256) void k_gemm_silu(float* __restrict__ h,
                                                   const float* __restrict__ W,
                                                   const float* __restrict__ bias,
                                                   int n1) {
    __shared__ float As[32 * DD];  // 32 KB
    const int t = threadIdx.x;
    const int row0 = blockIdx.x * 32;

    const float4* hv = (const float4*)h;
    float4* As4 = (float4*)As;
#pragma unroll
    for (int i = 0; i < 8; ++i) {
        int idx = t + i * 256;
        int r = idx >> 6, c = idx & 63;
        int gr = row0 + r;
        float4 v = make_float4(0.f, 0.f, 0.f, 0.f);
        if (gr < n1) v = hv[(size_t)gr * 64 + c];
        As4[idx] = v;
    }
    __syncthreads();

    const int rg = t >> 6;
    const int cg = t & 63;
    const float4* Wv = (const float4*)W;

    float4 acc[8];
#pragma unroll
    for (int r = 0; r < 8; ++r) acc[r] = make_float4(0.f, 0.f, 0.f, 0.f);

    for (int k = 0; k < DD; k += 4) {
        float4 a[8];
#pragma unroll
        for (int r = 0; r < 8; ++r)
            a[r] = *(const float4*)&As[(rg * 8 + r) * DD + k];
#pragma unroll
        for (int kk = 0; kk < 4; ++kk) {
            float4 w = Wv[(size_t)(k + kk) * 64 + cg];
#pragma unroll
            for (int r = 0; r < 8; ++r) {
                float av = (kk == 0) ? a[r].x : (kk == 1) ? a[r].y
                         : (kk == 2) ? a[r].z : a[r].w;
                acc[r].x += av * w.x;
                acc[r].y += av * w.y;
                acc[r].z += av * w.z;
                acc[r].w += av * w.w;
            }
        }
    }

    float4 bb = ((const float4*)bias)[cg];
    float4* ho = (float4*)h;
#pragma unroll
    for (int r = 0; r < 8; ++r) {
        int gr = row0 + rg * 8 + r;
        if (gr >= n1) continue;
        float4 x = acc[r];
        x.x = silu_f(x.x + bb.x);
        x.y = silu_f(x.y + bb.y);
        x.z = silu_f(x.z + bb.z);
        x.w = silu_f(x.w + bb.w);
        ho[(size_t)gr * 64 + cg] = x;
    }
}

// ================= launcher ================================================
static inline size_t al16(size_t x) { return (x + 15) & ~(size_t)15; }

extern "C" void kernel_launch(void* const* d_in, const int* in_sizes, int n_in,
                              void* d_out, int out_size, void* d_ws, size_t ws_size,
                              hipStream_t stream) {
    const float* feat = (const float*)d_in[0];
    const int* c2a = (const int*)d_in[1];
    const int* c2b = (const int*)d_in[2];
    const int* c3a = (const int*)d_in[3];
    const int* c3b = (const int*)d_in[4];
    const int* c4a = (const int*)d_in[5];
    const int* c4b = (const int*)d_in[6];
    const float* W = (const float*)d_in[7];
    const float* bias = (const float*)d_in[8];

    const int N1 = in_sizes[0] / DD;
    const int N2 = in_sizes[1];
    const int N3 = in_sizes[3];
    const int N4 = in_sizes[5];
    float* out = (float*)d_out;
    char* ws = (char*)d_ws;

    dim3 blk(256);
    auto rows_grid = [](int n) { return dim3((unsigned)((n + 3) / 4)); };
    auto thr_grid = [](int n) { return dim3((unsigned)((n + 255) / 256)); };

    int maxN = N1 > N2 ? N1 : N2;
    if (N3 > maxN) maxN = N3;

    // ---- scratch layout ----
    size_t cnt_b   = al16((size_t)maxN * 4);
    size_t bsum_b  = al16(4096);
    size_t offs4_b = al16((size_t)(N3 + 1) * 4);
    size_t entp_b  = al16((size_t)2 * N4 * 8);       // int2 per incidence
    size_t offs3_b = al16((size_t)(N2 + 1) * 4);
    size_t ent3_b  = al16((size_t)2 * N3 * 4);
    size_t offs2_b = al16((size_t)(N1 + 1) * 4);
    size_t ent2_b  = al16((size_t)2 * N2 * 4);
    size_t fixed_b = cnt_b + bsum_b + offs4_b + entp_b + offs3_b + ent3_b +
                     offs2_b + ent2_b;
    size_t h2h_b = (size_t)N2 * DH * sizeof(float);   // 51.2 MB
    size_t h3th_full_b = (size_t)N3 * DH * sizeof(float);  // 102.4 MB

    char* p = ws;
    int* cnt   = (int*)p; p += cnt_b;
    int* bsum  = (int*)p; p += bsum_b;
    int* offs4 = (int*)p; p += offs4_b;
    int2* entp = (int2*)p; p += entp_b;
    int* offs3 = (int*)p; p += offs3_b;
    int* ent3  = (int*)p; p += ent3_b;
    int* offs2 = (int*)p; p += offs2_b;
    int* ent2  = (int*)p; p += ent2_b;
    float* h2h = (float*)p; p += h2h_b;

    // primary: single-chunk h3th right after h2h; m2 in-place on h2h.
    bool single = (ws_size >= fixed_b + h2h_b + h3th_full_b);

    auto scan_offs = [&](int* cn, int nnode, int* offs) {
        int nb = (nnode + SCAN_ELEMS - 1) / SCAN_ELEMS;
        k_block_sums<<<dim3((unsigned)nb), dim3(SCAN_BLK), 0, stream>>>(cn, nnode, bsum);
        k_scan_bsums<<<dim3(1), dim3(64), 0, stream>>>(bsum, nb, offs + nnode);
        k_scan_final<<<dim3((unsigned)nb), dim3(SCAN_BLK), 0, stream>>>(cn, nnode, bsum, offs);
    };

    // ---- CSR4 with pair payload ----
    hipMemsetAsync(cnt, 0, (size_t)N3 * 4, stream);
    k_count_pairs<<<thr_grid(N4), blk, 0, stream>>>(c4a, c4b, N4, cnt);
    scan_offs(cnt, N3, offs4);
    hipMemcpyAsync(cnt, offs4, (size_t)N3 * 4, hipMemcpyDeviceToDevice, stream);
    k_fill_pairs4<<<thr_grid(N4), blk, 0, stream>>>(c4a, c4b, c3a, c3b, N4, cnt, entp);

    // ---- CSR3 (edge ids) ----
    hipMemsetAsync(cnt, 0, (size_t)N2 * 4, stream);
    k_count_pairs<<<thr_grid(N3), blk, 0, stream>>>(c3a, c3b, N3, cnt);
    scan_offs(cnt, N2, offs3);
    hipMemcpyAsync(cnt, offs3, (size_t)N2 * 4, hipMemcpyDeviceToDevice, stream);
    k_fill_edges<<<thr_grid(N3), blk, 0, stream>>>(c3a, c3b, N3, cnt, ent3);

    // ---- CSR2 (edge ids) ----
    hipMemsetAsync(cnt, 0, (size_t)N1 * 4, stream);
    k_count_pairs<<<thr_grid(N2), blk, 0, stream>>>(c2a, c2b, N2, cnt);
    scan_offs(cnt, N1, offs2);
    hipMemcpyAsync(cnt, offs2, (size_t)N1 * 4, hipMemcpyDeviceToDevice, stream);
    k_fill_edges<<<thr_grid(N2), blk, 0, stream>>>(c2a, c2b, N2, cnt, ent2);

    if (single) {
        float* h3th = (float*)p;
        for (int doff = 0; doff < DD; doff += DH) {
            k_h2_half<<<rows_grid(N2), blk, 0, stream>>>(feat, c2a, c2b, h2h, N2, doff);
            k_h3tot_half<<<rows_grid(N3), blk, 0, stream>>>(h2h, c3a, c3b, offs4, entp,
                                                            h3th, 0, N3);
            // m2 in place on h2h (all h3tot reads of h2h are complete)
            k_m2_half<<<rows_grid(N2), blk, 0, stream>>>(h2h, offs3, ent3, h3th,
                                                         h2h, N2, 0, N3, 1);
            k_h1_half<<<rows_grid(N1), blk, 0, stream>>>(feat, h2h, offs2, ent2,
                                                         out, N1, doff);
        }
    } else {
        // chunked fallback: separate m2h buffer; h3th chunks after it
        float* m2h = (float*)p;
        char* pc = p + h2h_b;  // m2h same size as h2h
        float* h3th = (float*)pc;
        size_t free_b = (ws_size > fixed_b + 2 * h2h_b) ? ws_size - fixed_b - 2 * h2h_b : 0;
        int chunk_rows = (int)(free_b / ((size_t)DH * sizeof(float)));
        if (chunk_rows > N3) chunk_rows = N3;
        if (chunk_rows < 1) chunk_rows = 1;
        int C = (N3 + chunk_rows - 1) / chunk_rows;
        chunk_rows = (N3 + C - 1) / C;

        for (int doff = 0; doff < DD; doff += DH) {
            k_h2_half<<<rows_grid(N2), blk, 0, stream>>>(feat, c2a, c2b, h2h, N2, doff);
            int first = 1;
            for (int lo = 0; lo < N3; lo += chunk_rows) {
                int hi = lo + chunk_rows;
                if (hi > N3) hi = N3;
                k_h3tot_half<<<rows_grid(hi - lo), blk, 0, stream>>>(h2h, c3a, c3b,
                                                                     offs4, entp,
                                                                     h3th, lo, hi);
                k_m2_half<<<rows_grid(N2), blk, 0, stream>>>(h2h, offs3, ent3, h3th,
                                                             m2h, N2, lo, hi, first);
                first = 0;
            }
            k_h1_half<<<rows_grid(N1), blk, 0, stream>>>(feat, m2h, offs2, ent2,
                                                         out, N1, doff);
        }
    }

    // out = silu(out @ W + b), in-place
    k_gemm_silu<<<dim3((unsigned)((N1 + 31) / 32)), blk, 0, stream>>>(out, W, bias, N1);
}